// Round 4
// baseline (287.384 us; speedup 1.0000x reference)
//
#include <hip/hip_runtime.h>
#include <hip/hip_bf16.h>
#include <stdint.h>

#define NN 4096

// Round-24 restructure: a4 = A * (a2 * A).
//   cra2_k builds a2(v) in LDS, then a3row(v) = sum_u a2[v,u]*Arow(u) in LDS,
//   and emits a3 as a DENSE u8 row (4096 B, values <= ~90 << 255).
//   a4row_k computes a4row(v) = sum_{u in N(v)} a3row(u): 17 weight-1 sources,
//   uniform work (256 uint4 per source), implicit columns.
// LDS accumulator is stored XOR-swizzled: accS(col) = col ^ ((col>>5)&15).
//   For byte k of chunk d (col = 16d+k), accS = 16d + (k ^ h), h=(d>>1)&15
//   -> per instruction k, 64 consecutive d hit every bank exactly twice
//   (exact 2-way = free). Top-8 / zeroing are permutation-agnostic.

// ---------------------------------------------------------------------------
// K1: scan_k — one pass over adj per row with float4 loads (16 B/lane).
// Bit layout of abits (must match cr-role reads): for element e,
//   word(e) = ((e>>8)<<2) | (e&3),  bit(e) = (e>>2)&63.
// nbr list order is scrambled vs ascending — all consumers set-order-agnostic.
// ---------------------------------------------------------------------------
__global__ __launch_bounds__(256) void scan_k(const float* __restrict__ adj,
                                              int* __restrict__ nbr,
                                              int* __restrict__ deg,
                                              unsigned long long* __restrict__ abits,
                                              float* __restrict__ feats) {
    __shared__ int nlist[4][64];
    int tid = threadIdx.x;
    int wv = tid >> 6, ln = tid & 63;
    int v = blockIdx.x * 4 + wv;
    size_t rb = (size_t)v * NN;
    int total = 0;
    unsigned long long w0 = 0;
    const float4* row4 = (const float4*)(adj + rb);
    for (int base = 0; base < NN; base += 256) {
        float4 f = row4[(base >> 2) + ln];
        int q4 = (base >> 8) << 2;
        #pragma unroll
        for (int j = 0; j < 4; j++) {
            float vj = (j == 0) ? f.x : (j == 1) ? f.y : (j == 2) ? f.z : f.w;
            unsigned long long m = __ballot(vj > 0.5f);
            if (vj > 0.5f) {
                int pos = total + __popcll(m & ((1ull << ln) - 1ull));
                if (pos < 64) nlist[wv][pos] = base + 4 * ln + j;
            }
            if (ln == q4 + j) w0 = m;
            total += __popcll(m);
        }
    }
    abits[(size_t)v * 64 + ln] = w0;
    int degL = min(total, 64);
    if (ln < degL) nbr[v * 64 + ln] = nlist[wv][ln];
    if (ln == 0) {
        deg[v] = total;
        float degf = (float)total;
        feats[v * 16 + 12] = degf;
        feats[v * 16 + 13] = degf * degf;
        feats[v * 16 + 14] = degf;           // diag(A^2) = deg (symmetric 0/1)
    }
}

// ---------------------------------------------------------------------------
// K2: cra2_k — role-split merged dispatch:
//   blocks [0, 4096):    a2 (LDS) -> source list -> a3 (LDS) -> dense u8 row
//   blocks [4096, 5120): cr_feat from the L2-resident bitmask (4 nodes/block)
// ---------------------------------------------------------------------------
__global__ __launch_bounds__(256) void cra2_k(const unsigned long long* __restrict__ abits,
                                              const int* __restrict__ nbr,
                                              const int* __restrict__ deg,
                                              unsigned int* __restrict__ a3d,
                                              float* __restrict__ feats) {
    __shared__ __align__(64) unsigned int smem[NN + 132 + 640];
    int tid = threadIdx.x;
    int bid = blockIdx.x;
    int wv = tid >> 6, ln = tid & 63;

    if (bid < NN) {
        // ------------------- a2 -> a3 role -------------------
        unsigned int* acc   = smem;                     // [4096]
        int* us             = (int*)(smem + NN);        // [64]
        int* dus            = (int*)(smem + NN + 64);   // [64]
        unsigned int* wsumS = smem + NN + 128;          // [4]
        unsigned int* srcL  = smem + NN + 132;          // [640] (w<<19)|(dgu<<12)|col
        int v = bid;
        uint4 z = {0u, 0u, 0u, 0u};
        #pragma unroll
        for (int i = 0; i < 4; i++) ((uint4*)acc)[tid + 256 * i] = z;
        int dv = min(deg[v], 64);
        if (tid < dv) {
            int u = nbr[v * 64 + tid];
            us[tid] = u;
            dus[tid] = min(deg[u], 64);
        }
        __syncthreads();
        // a2 scatter: acc[x] = a2[v][x]
        for (int p = tid; p < dv * 64; p += 256) {
            int i = p >> 6, wi = p & 63;
            if (wi < dus[i]) atomicAdd(&acc[nbr[us[i] * 64 + wi]], 1u);
        }
        __syncthreads();
        // build compact source list (col, full weight, deg(col))
        unsigned int myw[16];
        int local = 0;
        #pragma unroll
        for (int m = 0; m < 16; m++) {
            unsigned int a = acc[tid + 256 * m];
            myw[m] = a;
            local += (a != 0u);
        }
        int incl = local;
        #pragma unroll
        for (int off = 1; off < 64; off <<= 1) {
            int n = __shfl_up(incl, off, 64);
            if (ln >= off) incl += n;
        }
        if (ln == 63) wsumS[wv] = (unsigned int)incl;
        __syncthreads();
        unsigned int wpre = 0, nsrc = 0;
        #pragma unroll
        for (int q = 0; q < 4; q++) {
            unsigned int s = wsumS[q];
            if (q < wv) wpre += s;
            nsrc += s;
        }
        unsigned int pos = wpre + (unsigned int)(incl - local);
        #pragma unroll
        for (int m = 0; m < 16; m++) {
            unsigned int a = myw[m];
            if (a) {
                unsigned int col = (unsigned int)tid + 256u * m;
                unsigned int dgu = (unsigned int)min(deg[col], 64);
                if (pos < 640u) srcL[pos] = (a << 19) | (dgu << 12) | col;
                pos++;
            }
        }
        if (nsrc > 640u) nsrc = 640u;
        __syncthreads();
        // re-zero acc, then a3 scatter: acc[x] = sum_u a2[v,u]*A[u,x]
        #pragma unroll
        for (int i = 0; i < 4; i++) ((uint4*)acc)[tid + 256 * i] = z;
        __syncthreads();
        int lim = (int)nsrc * 64;
        for (int q = tid; q < lim; q += 256) {
            int i = q >> 6, j = q & 63;
            unsigned int e = srcL[i];
            if (j < (int)((e >> 12) & 0x7Fu))
                atomicAdd(&acc[nbr[(e & 0xFFFu) * 64 + j]], e >> 19);
        }
        __syncthreads();
        // dense u8 emit: thread packs cols [16*tid, 16*tid+16)
        {
            int base = tid * 16;
            unsigned int w0 = 0, w1 = 0, w2 = 0, w3 = 0;
            #pragma unroll
            for (int i = 0; i < 4; i++) w0 |= min(acc[base + i], 255u) << (8 * i);
            #pragma unroll
            for (int i = 0; i < 4; i++) w1 |= min(acc[base + 4 + i], 255u) << (8 * i);
            #pragma unroll
            for (int i = 0; i < 4; i++) w2 |= min(acc[base + 8 + i], 255u) << (8 * i);
            #pragma unroll
            for (int i = 0; i < 4; i++) w3 |= min(acc[base + 12 + i], 255u) << (8 * i);
            uint4 o; o.x = w0; o.y = w1; o.z = w2; o.w = w3;
            ((uint4*)((char*)a3d + (size_t)v * 4096))[tid] = o;
        }
    } else {
        // ------------------- cr role -------------------
        unsigned long long* rows = (unsigned long long*)smem;   // [4][64], 2 KB
        int* mems = (int*)(smem + 1024);                        // [4][64], 1 KB
        int v = (bid - NN) * 4 + wv;

        int dv = deg[v];
        int degL = min(dv, 64);
        int c = min(dv + 1, 64);

        int nl = (ln < degL) ? nbr[v * 64 + ln] : 0;
        int isless = (ln < degL && nl < v) ? 1 : 0;
        int pos = isless;
        #pragma unroll
        for (int off = 32; off; off >>= 1) pos += __shfl_xor(pos, off, 64);

        int mem = 0;
        if (ln < c) {
            if (ln < pos)       mem = nl;
            else if (ln == pos) mem = v;
            else                mem = nbr[v * 64 + ln - 1];
        }
        mems[wv * 64 + ln] = mem;
        __syncthreads();

        unsigned long long mask = 0ull;
        {
            const unsigned long long* rowb = abits + (size_t)mem * 64;
            for (int j = 0; j < c; j++) {
                int mj = mems[wv * 64 + j];
                unsigned long long w = rowb[((mj >> 8) << 2) | (mj & 3)];
                mask |= ((w >> ((mj >> 2) & 63)) & 1ull) << j;
            }
        }
        if (ln >= c) mask = 0ull;
        rows[wv * 64 + ln] = mask;
        __syncthreads();

        int tpart = 0;
        float epart = 0.f, wpart = 0.f;
        if (ln < c) {
            unsigned long long mm = mask;
            while (mm) {
                int j = __ffsll(mm) - 1;
                mm &= mm - 1;
                tpart += __popcll(mask & rows[wv * 64 + j]);
            }
            if (ln != pos) {
                int cn = __popcll(rows[wv * 64 + pos] & mask);
                float D2 = (float)cn + 1.0f;
                epart = D2;
                wpart = D2 * (D2 - 1.0f) * 0.5f;
            }
        }
        float es = epart, wsum2 = wpart;
        int ts = tpart;
        #pragma unroll
        for (int off = 32; off; off >>= 1) {
            es += __shfl_xor(es, off, 64);
            wsum2 += __shfl_xor(wsum2, off, 64);
            ts += __shfl_xor(ts, off, 64);
        }

        if (ln == 0) {
            float degf = (float)dv;
            float k = degf + 1.0f;
            float E = 0.5f * (es + degf);
            float W = wsum2 + degf * (degf - 1.0f) * 0.5f;
            float T = (float)ts / 6.0f;
            float f3 = T;
            float f2 = W - 3.0f * T;
            float f1 = E * (k - 2.0f) - 2.0f * f2 - 3.0f * f3;
            float tot2 = k * (k - 1.0f) * (k - 2.0f) / 6.0f;
            float f0 = tot2 - f1 - f2 - f3;
            if (k < 3.0f) { f0 = f1 = f2 = f3 = 0.f; }
            float s = f0 + f1 + f2 + f3 + 1e-10f;
            feats[v * 16 + 0] = f0 / s;
            feats[v * 16 + 1] = f1 / s;
            feats[v * 16 + 2] = f2 / s;
            feats[v * 16 + 3] = f3 / s;
        }
    }
}

// ---------------------------------------------------------------------------
// K3: order_k — counting sort of rows by deg DESCENDING (a4 work ∝ deg now).
// ---------------------------------------------------------------------------
__global__ __launch_bounds__(1024) void order_k(const int* __restrict__ deg,
                                                int* __restrict__ ord) {
    __shared__ unsigned int bcnt[192];
    __shared__ unsigned int bbase[192];
    int tid = threadIdx.x;
    if (tid < 192) bcnt[tid] = 0u;
    __syncthreads();
    unsigned char myk[4];
    #pragma unroll
    for (int j = 0; j < 4; j++) {
        int v = tid * 4 + j;
        myk[j] = (unsigned char)min(deg[v], 191);
        atomicAdd(&bcnt[myk[j]], 1u);
    }
    __syncthreads();
    if (tid == 0) {
        unsigned int run = 0;
        for (int b = 191; b >= 0; b--) { bbase[b] = run; run += bcnt[b]; }
    }
    __syncthreads();
    #pragma unroll
    for (int j = 0; j < 4; j++) {
        int v = tid * 4 + j;
        unsigned int p = atomicAdd(&bbase[myk[j]], 1u);
        ord[p] = v;
    }
}

// ---------------------------------------------------------------------------
// K4: fused a4-row (dense-u8 a3 sources, weight 1) + top-8 + embedding.
// acc is XOR-swizzled (accS(col) = col ^ ((col>>5)&15)): per byte-slot k the
// 64 lanes (consecutive chunks d) hit each bank exactly twice. Top-8 scans
// all 4096 slots — permutation-agnostic.
// ---------------------------------------------------------------------------
#define DO4(word, kb) \
    atomicAdd(&acc[a1e ^ (kb + 0u)], (word) & 0xFFu);          \
    atomicAdd(&acc[a1e ^ (kb + 1u)], ((word) >> 8) & 0xFFu);   \
    atomicAdd(&acc[a1e ^ (kb + 2u)], ((word) >> 16) & 0xFFu);  \
    atomicAdd(&acc[a1e ^ (kb + 3u)], (word) >> 24);

__global__ __launch_bounds__(512) void a4row_k(const uint4* __restrict__ a3d4,
                                               const int* __restrict__ deg,
                                               const int* __restrict__ nbr,
                                               const int* __restrict__ ord,
                                               const float* __restrict__ feats,
                                               const float* __restrict__ e_w,
                                               const float* __restrict__ e_b,
                                               float* __restrict__ x0) {
    __shared__ __align__(64) unsigned int acc[NN];         // 16 KB
    __shared__ unsigned int sbase[64];
    __shared__ unsigned int wtops[64];
    int tid = threadIdx.x;
    int wv = tid >> 6, ln = tid & 63;
    int v = ord[blockIdx.x];

    {
        uint4 z = {0u, 0u, 0u, 0u};
        #pragma unroll
        for (int i = 0; i < 2; i++) ((uint4*)acc)[tid + 512 * i] = z;
    }
    int dvv = min(deg[v], 64);
    if (tid < dvv) sbase[tid] = (unsigned int)nbr[v * 64 + tid] * 256u;
    __syncthreads();

    int tot = dvv << 8;
    for (int g = tid; g < tot; g += 512) {
        unsigned int d = (unsigned int)g & 255u;
        uint4 E = a3d4[sbase[g >> 8] + d];
        unsigned int a1e = (d << 4) + ((d >> 1) & 15u);    // 16d + h
        DO4(E.x, 0u)
        DO4(E.y, 4u)
        DO4(E.z, 8u)
        DO4(E.w, 12u)
    }
    __syncthreads();

    // per-thread top-8 over 8 conflict-free LDS reads
    unsigned int best[8];
    #pragma unroll
    for (int q = 0; q < 8; q++) best[q] = 0u;
    #pragma unroll
    for (int m = 0; m < 8; m++) {
        unsigned int val = acc[tid + 512 * m];
        if (val > best[7]) {
            best[7] = val;
            #pragma unroll
            for (int s = 7; s > 0; s--) {
                if (best[s] > best[s - 1]) {
                    unsigned int t2 = best[s - 1]; best[s - 1] = best[s]; best[s] = t2;
                } else break;
            }
        }
    }

    // per-wave extract of 8 maxima (shfl-only)
    unsigned int wave_val = 0u;
    #pragma unroll
    for (int r = 0; r < 8; r++) {
        unsigned int m = best[0];
        #pragma unroll
        for (int off = 32; off; off >>= 1)
            m = max(m, (unsigned int)__shfl_xor((int)m, off, 64));
        unsigned long long bb = __ballot(best[0] == m);
        int src = __ffsll(bb) - 1;
        if (ln == src) {
            #pragma unroll
            for (int s = 0; s < 7; s++) best[s] = best[s + 1];
            best[7] = 0u;
        }
        if (ln == r) wave_val = m;
    }
    if (ln < 8) wtops[wv * 8 + ln] = wave_val;
    __syncthreads();

    // wave 0: merge 64 candidates, then fused embedding
    if (wv == 0) {
        unsigned int cand = wtops[ln];
        unsigned int myv = 0u;
        #pragma unroll
        for (int r = 0; r < 8; r++) {
            unsigned int m = cand;
            #pragma unroll
            for (int off = 32; off; off >>= 1)
                m = max(m, (unsigned int)__shfl_xor((int)m, off, 64));
            unsigned long long bb = __ballot(cand == m);
            int src = __ffsll(bb) - 1;
            if (ln == src) cand = 0u;
            if (ln == r) myv = m;
        }
        int d = ln;
        float s = e_b[d];
        s += feats[v * 16 + 0]  * e_w[0 * 64 + d];
        s += feats[v * 16 + 1]  * e_w[1 * 64 + d];
        s += feats[v * 16 + 2]  * e_w[2 * 64 + d];
        s += feats[v * 16 + 3]  * e_w[3 * 64 + d];
        #pragma unroll
        for (int j = 0; j < 8; j++) {
            float mj = (float)(unsigned int)__shfl((int)myv, j, 64);
            s += mj * e_w[(4 + j) * 64 + d];
        }
        s += feats[v * 16 + 12] * e_w[12 * 64 + d];
        s += feats[v * 16 + 13] * e_w[13 * 64 + d];
        s += feats[v * 16 + 14] * e_w[14 * 64 + d];
        x0[(size_t)v * 64 + d] = s;
    }
}

// ---------------------------------------------------------------------------
// K5: one GNN layer, weights LDS-staged. For li==2, accumulate block column
// sums directly into out[64] via fp32 atomics.
// ---------------------------------------------------------------------------
__global__ __launch_bounds__(256) void layer_k(const float* __restrict__ xin,
                                               float* __restrict__ xout,
                                               const float* __restrict__ w1,
                                               const float* __restrict__ b1,
                                               const float* __restrict__ w2,
                                               const float* __restrict__ b2,
                                               const float* __restrict__ eps,
                                               const int* __restrict__ nbr,
                                               const int* __restrict__ deg,
                                               float* __restrict__ out,
                                               int li) {
    __shared__ float wL[4096];                // 16 KB, reused for w1 then w2
    __shared__ float h[4][64], t[4][64];
    int tid = threadIdx.x;
    int wv = tid >> 6, d = tid & 63;
    int v = blockIdx.x * 4 + wv;

    // stage w1 (coalesced float4)
    {
        const float4* src = (const float4*)(w1 + li * 4096);
        #pragma unroll
        for (int i = 0; i < 4; i++) ((float4*)wL)[tid + 256 * i] = src[tid + 256 * i];
    }

    float xv = xin[(size_t)v * 64 + d];
    int dv = min(deg[v], 64);
    const int* nl = nbr + v * 64;
    float agg = 0.f;
    int j = 0;
    for (; j + 4 <= dv; j += 4) {
        int n0 = nl[j], n1 = nl[j + 1], n2 = nl[j + 2], n3 = nl[j + 3];
        float a0 = xin[(size_t)n0 * 64 + d];
        float a1 = xin[(size_t)n1 * 64 + d];
        float a2v = xin[(size_t)n2 * 64 + d];
        float a3 = xin[(size_t)n3 * 64 + d];
        agg += (a0 + a1) + (a2v + a3);
    }
    for (; j < dv; j++) agg += xin[(size_t)nl[j] * 64 + d];
    float hv = (1.0f + eps[li]) * xv + agg;
    h[wv][d] = hv;
    __syncthreads();

    float s = b1[li * 64 + d];
    #pragma unroll 8
    for (int k = 0; k < 64; k++) s += h[wv][k] * wL[k * 64 + d];
    s = fmaxf(s, 0.f);
    t[wv][d] = s;
    __syncthreads();

    // stage w2 (reuse wL)
    {
        const float4* src = (const float4*)(w2 + li * 4096);
        #pragma unroll
        for (int i = 0; i < 4; i++) ((float4*)wL)[tid + 256 * i] = src[tid + 256 * i];
    }
    __syncthreads();

    float o = b2[li * 64 + d];
    #pragma unroll 8
    for (int k = 0; k < 64; k++) o += t[wv][k] * wL[k * 64 + d];
    if (li == 2) {
        h[wv][d] = o;
        __syncthreads();
        if (wv == 0)
            atomicAdd(&out[d], (h[0][d] + h[1][d]) + (h[2][d] + h[3][d]));
    } else {
        xout[(size_t)v * 64 + d] = o;
    }
}

// ---------------------------------------------------------------------------
extern "C" void kernel_launch(void* const* d_in, const int* in_sizes, int n_in,
                              void* d_out, int out_size, void* d_ws, size_t ws_size,
                              hipStream_t stream) {
    const float* adj = (const float*)d_in[0];
    const float* e_w = (const float*)d_in[1];
    const float* e_b = (const float*)d_in[2];
    const float* w1  = (const float*)d_in[3];
    const float* b1  = (const float*)d_in[4];
    const float* w2  = (const float*)d_in[5];
    const float* b2  = (const float*)d_in[6];
    const float* eps = (const float*)d_in[7];
    float* out = (float*)d_out;

    char* ws = (char*)d_ws;
    unsigned int*       a3d     = (unsigned int*)(ws);                  // 16 MB dense u8 a3
    int*                nbr     = (int*)(ws + 25165824);                // 1 MB
    int*                deg     = (int*)(ws + 26214400);                // 16 KB
    float*              feats   = (float*)(ws + 26247168);              // 256 KB
    float*              x0      = (float*)(ws + 26509312);              // 1 MB
    float*              x1      = (float*)(ws + 27557888);              // 1 MB
    unsigned long long* abits   = (unsigned long long*)(ws + 28868608); // 2 MB
    int*                ord     = (int*)(ws + 30969856);                // 16 KB

    hipMemsetAsync(out, 0, 64 * sizeof(float), stream);
    scan_k<<<1024, 256, 0, stream>>>(adj, nbr, deg, abits, feats);
    cra2_k<<<5120, 256, 0, stream>>>(abits, nbr, deg, a3d, feats);
    order_k<<<1, 1024, 0, stream>>>(deg, ord);
    a4row_k<<<4096, 512, 0, stream>>>((const uint4*)a3d, deg, nbr, ord, feats, e_w, e_b, x0);
    layer_k<<<1024, 256, 0, stream>>>(x0, x1, w1, b1, w2, b2, eps, nbr, deg, out, 0);
    layer_k<<<1024, 256, 0, stream>>>(x1, x0, w1, b1, w2, b2, eps, nbr, deg, out, 1);
    layer_k<<<1024, 256, 0, stream>>>(x0, x1, w1, b1, w2, b2, eps, nbr, deg, out, 2);
}

// Round 5
// 265.339 us; speedup vs baseline: 1.0831x; 1.0831x over previous
//
#include <hip/hip_runtime.h>
#include <hip/hip_bf16.h>
#include <stdint.h>

#define NN 4096

// Round-25: a4 = A * (a2 * A) with u16-PACKED LDS accumulation in a4row_k.
//   cra2_k builds a2(v) in LDS, then a3row(v) = sum_u a2[v,u]*Arow(u) in LDS
//   (2 sources per wave-instr), emits a3 as DENSE u8 row (4096 B).
//   a4row_k: a4row(v) = sum_{u in N(v)} a3row(u), 17 weight-1 sources.
// a4 accumulator: 2048 u32 words, word w_logical = pair j of chunk d holds
// cols {16d+2j, 16d+2j+1} as two u16 lanes (max a4 = 64*255 < 2^16, no carry).
// Swizzled address: addr(d,j) = ((d<<3)|((d>>2)&7)) ^ j. Per instruction j,
// 64 consecutive d hit bank ((ln&3)<<3)|(((ln>>2)&7)^j): bijective in ln&31
// -> every bank exactly 2 lanes (free). addr>>3 == d (XOR only low 3 bits),
// so the map is bijective; top-8 unpacks lo/hi u16 (permutation-agnostic).

// ---------------------------------------------------------------------------
// K1: scan_k — one pass over adj per row with float4 loads (16 B/lane).
// Bit layout of abits (must match cr-role reads): for element e,
//   word(e) = ((e>>8)<<2) | (e&3),  bit(e) = (e>>2)&63.
// nbr list order is scrambled vs ascending — all consumers set-order-agnostic.
// ---------------------------------------------------------------------------
__global__ __launch_bounds__(256) void scan_k(const float* __restrict__ adj,
                                              int* __restrict__ nbr,
                                              int* __restrict__ deg,
                                              unsigned long long* __restrict__ abits,
                                              float* __restrict__ feats) {
    __shared__ int nlist[4][64];
    int tid = threadIdx.x;
    int wv = tid >> 6, ln = tid & 63;
    int v = blockIdx.x * 4 + wv;
    size_t rb = (size_t)v * NN;
    int total = 0;
    unsigned long long w0 = 0;
    const float4* row4 = (const float4*)(adj + rb);
    for (int base = 0; base < NN; base += 256) {
        float4 f = row4[(base >> 2) + ln];
        int q4 = (base >> 8) << 2;
        #pragma unroll
        for (int j = 0; j < 4; j++) {
            float vj = (j == 0) ? f.x : (j == 1) ? f.y : (j == 2) ? f.z : f.w;
            unsigned long long m = __ballot(vj > 0.5f);
            if (vj > 0.5f) {
                int pos = total + __popcll(m & ((1ull << ln) - 1ull));
                if (pos < 64) nlist[wv][pos] = base + 4 * ln + j;
            }
            if (ln == q4 + j) w0 = m;
            total += __popcll(m);
        }
    }
    abits[(size_t)v * 64 + ln] = w0;
    int degL = min(total, 64);
    if (ln < degL) nbr[v * 64 + ln] = nlist[wv][ln];
    if (ln == 0) {
        deg[v] = total;
        float degf = (float)total;
        feats[v * 16 + 12] = degf;
        feats[v * 16 + 13] = degf * degf;
        feats[v * 16 + 14] = degf;           // diag(A^2) = deg (symmetric 0/1)
    }
}

// ---------------------------------------------------------------------------
// K2: cra2_k — role-split merged dispatch:
//   blocks [0, 4096):    a2 (LDS) -> source list -> a3 (LDS) -> dense u8 row
//   blocks [4096, 5120): cr_feat from the L2-resident bitmask (4 nodes/block)
// ---------------------------------------------------------------------------
__global__ __launch_bounds__(256) void cra2_k(const unsigned long long* __restrict__ abits,
                                              const int* __restrict__ nbr,
                                              const int* __restrict__ deg,
                                              unsigned int* __restrict__ a3d,
                                              float* __restrict__ feats) {
    __shared__ __align__(64) unsigned int smem[NN + 132 + 640];
    int tid = threadIdx.x;
    int bid = blockIdx.x;
    int wv = tid >> 6, ln = tid & 63;

    if (bid < NN) {
        // ------------------- a2 -> a3 role -------------------
        unsigned int* acc   = smem;                     // [4096]
        int* us             = (int*)(smem + NN);        // [64]
        int* dus            = (int*)(smem + NN + 64);   // [64]
        unsigned int* wsumS = smem + NN + 128;          // [4]
        unsigned int* srcL  = smem + NN + 132;          // [640] (w<<19)|(dgu<<12)|col
        int v = bid;
        uint4 z = {0u, 0u, 0u, 0u};
        #pragma unroll
        for (int i = 0; i < 4; i++) ((uint4*)acc)[tid + 256 * i] = z;
        int dv = min(deg[v], 64);
        if (tid < dv) {
            int u = nbr[v * 64 + tid];
            us[tid] = u;
            dus[tid] = min(deg[u], 64);
        }
        __syncthreads();
        // a2 scatter: acc[x] = a2[v][x]
        for (int p = tid; p < dv * 64; p += 256) {
            int i = p >> 6, wi = p & 63;
            if (wi < dus[i]) atomicAdd(&acc[nbr[us[i] * 64 + wi]], 1u);
        }
        __syncthreads();
        // build compact source list (col, full weight, deg(col))
        unsigned int myw[16];
        int local = 0;
        #pragma unroll
        for (int m = 0; m < 16; m++) {
            unsigned int a = acc[tid + 256 * m];
            myw[m] = a;
            local += (a != 0u);
        }
        int incl = local;
        #pragma unroll
        for (int off = 1; off < 64; off <<= 1) {
            int n = __shfl_up(incl, off, 64);
            if (ln >= off) incl += n;
        }
        if (ln == 63) wsumS[wv] = (unsigned int)incl;
        __syncthreads();
        unsigned int wpre = 0, nsrc = 0;
        #pragma unroll
        for (int q = 0; q < 4; q++) {
            unsigned int s = wsumS[q];
            if (q < wv) wpre += s;
            nsrc += s;
        }
        unsigned int pos = wpre + (unsigned int)(incl - local);
        #pragma unroll
        for (int m = 0; m < 16; m++) {
            unsigned int a = myw[m];
            if (a) {
                unsigned int col = (unsigned int)tid + 256u * m;
                unsigned int dgu = (unsigned int)min(deg[col], 64);
                if (pos < 640u) srcL[pos] = (a << 19) | (dgu << 12) | col;
                pos++;
            }
        }
        if (nsrc > 640u) nsrc = 640u;
        __syncthreads();
        // re-zero acc, then a3 scatter: acc[x] = sum_u a2[v,u]*A[u,x]
        // 2 sources per wave-instr: lane -> source 2*i2+(ln>>5), j = ln&31.
        // dgu>32 tail (P ~ 3e-5) handled serially on the j==31 lane.
        #pragma unroll
        for (int i = 0; i < 4; i++) ((uint4*)acc)[tid + 256 * i] = z;
        __syncthreads();
        int lim64 = (((int)nsrc + 1) >> 1) << 6;
        for (int q = tid; q < lim64; q += 256) {
            int s = (q >> 5) & ~0;           // s = 2*(q>>6) + ((q>>5)&1)
            s = ((q >> 6) << 1) | ((q >> 5) & 1);
            int j = q & 31;
            if (s < (int)nsrc) {
                unsigned int e = srcL[s];
                int dgu = (int)((e >> 12) & 0x7Fu);
                unsigned int w = e >> 19;
                const int* nru = nbr + (e & 0xFFFu) * 64;
                if (j < dgu) atomicAdd(&acc[nru[j]], w);
                if (j == 31) {
                    for (int jj = 32; jj < dgu; jj++) atomicAdd(&acc[nru[jj]], w);
                }
            }
        }
        __syncthreads();
        // dense u8 emit: thread packs cols [16*tid, 16*tid+16)
        {
            int base = tid * 16;
            unsigned int w0 = 0, w1 = 0, w2 = 0, w3 = 0;
            #pragma unroll
            for (int i = 0; i < 4; i++) w0 |= min(acc[base + i], 255u) << (8 * i);
            #pragma unroll
            for (int i = 0; i < 4; i++) w1 |= min(acc[base + 4 + i], 255u) << (8 * i);
            #pragma unroll
            for (int i = 0; i < 4; i++) w2 |= min(acc[base + 8 + i], 255u) << (8 * i);
            #pragma unroll
            for (int i = 0; i < 4; i++) w3 |= min(acc[base + 12 + i], 255u) << (8 * i);
            uint4 o; o.x = w0; o.y = w1; o.z = w2; o.w = w3;
            ((uint4*)((char*)a3d + (size_t)v * 4096))[tid] = o;
        }
    } else {
        // ------------------- cr role -------------------
        unsigned long long* rows = (unsigned long long*)smem;   // [4][64], 2 KB
        int* mems = (int*)(smem + 1024);                        // [4][64], 1 KB
        int v = (bid - NN) * 4 + wv;

        int dv = deg[v];
        int degL = min(dv, 64);
        int c = min(dv + 1, 64);

        int nl = (ln < degL) ? nbr[v * 64 + ln] : 0;
        int isless = (ln < degL && nl < v) ? 1 : 0;
        int pos = isless;
        #pragma unroll
        for (int off = 32; off; off >>= 1) pos += __shfl_xor(pos, off, 64);

        int mem = 0;
        if (ln < c) {
            if (ln < pos)       mem = nl;
            else if (ln == pos) mem = v;
            else                mem = nbr[v * 64 + ln - 1];
        }
        mems[wv * 64 + ln] = mem;
        __syncthreads();

        unsigned long long mask = 0ull;
        {
            const unsigned long long* rowb = abits + (size_t)mem * 64;
            for (int j = 0; j < c; j++) {
                int mj = mems[wv * 64 + j];
                unsigned long long w = rowb[((mj >> 8) << 2) | (mj & 3)];
                mask |= ((w >> ((mj >> 2) & 63)) & 1ull) << j;
            }
        }
        if (ln >= c) mask = 0ull;
        rows[wv * 64 + ln] = mask;
        __syncthreads();

        int tpart = 0;
        float epart = 0.f, wpart = 0.f;
        if (ln < c) {
            unsigned long long mm = mask;
            while (mm) {
                int j = __ffsll(mm) - 1;
                mm &= mm - 1;
                tpart += __popcll(mask & rows[wv * 64 + j]);
            }
            if (ln != pos) {
                int cn = __popcll(rows[wv * 64 + pos] & mask);
                float D2 = (float)cn + 1.0f;
                epart = D2;
                wpart = D2 * (D2 - 1.0f) * 0.5f;
            }
        }
        float es = epart, wsum2 = wpart;
        int ts = tpart;
        #pragma unroll
        for (int off = 32; off; off >>= 1) {
            es += __shfl_xor(es, off, 64);
            wsum2 += __shfl_xor(wsum2, off, 64);
            ts += __shfl_xor(ts, off, 64);
        }

        if (ln == 0) {
            float degf = (float)dv;
            float k = degf + 1.0f;
            float E = 0.5f * (es + degf);
            float W = wsum2 + degf * (degf - 1.0f) * 0.5f;
            float T = (float)ts / 6.0f;
            float f3 = T;
            float f2 = W - 3.0f * T;
            float f1 = E * (k - 2.0f) - 2.0f * f2 - 3.0f * f3;
            float tot2 = k * (k - 1.0f) * (k - 2.0f) / 6.0f;
            float f0 = tot2 - f1 - f2 - f3;
            if (k < 3.0f) { f0 = f1 = f2 = f3 = 0.f; }
            float s = f0 + f1 + f2 + f3 + 1e-10f;
            feats[v * 16 + 0] = f0 / s;
            feats[v * 16 + 1] = f1 / s;
            feats[v * 16 + 2] = f2 / s;
            feats[v * 16 + 3] = f3 / s;
        }
    }
}

// ---------------------------------------------------------------------------
// K3: order_k — counting sort of rows by deg DESCENDING (a4 work ∝ deg).
// ---------------------------------------------------------------------------
__global__ __launch_bounds__(1024) void order_k(const int* __restrict__ deg,
                                                int* __restrict__ ord) {
    __shared__ unsigned int bcnt[192];
    __shared__ unsigned int bbase[192];
    int tid = threadIdx.x;
    if (tid < 192) bcnt[tid] = 0u;
    __syncthreads();
    unsigned char myk[4];
    #pragma unroll
    for (int j = 0; j < 4; j++) {
        int v = tid * 4 + j;
        myk[j] = (unsigned char)min(deg[v], 191);
        atomicAdd(&bcnt[myk[j]], 1u);
    }
    __syncthreads();
    if (tid == 0) {
        unsigned int run = 0;
        for (int b = 191; b >= 0; b--) { bbase[b] = run; run += bcnt[b]; }
    }
    __syncthreads();
    #pragma unroll
    for (int j = 0; j < 4; j++) {
        int v = tid * 4 + j;
        unsigned int p = atomicAdd(&bbase[myk[j]], 1u);
        ord[p] = v;
    }
}

// ---------------------------------------------------------------------------
// K4: fused a4-row (dense-u8 a3 sources, weight 1) + top-8 + embedding.
// u16-packed accumulation: 8 ds_add per uint4 (2 cols per add). Exact 2-way
// banking via addr(d,j) = ((d<<3)|((d>>2)&7)) ^ j.
// ---------------------------------------------------------------------------
#define DOPAIRS(word, jb) \
    { unsigned int p0 = ((word) & 0xFFu) | (((word) & 0xFF00u) << 8);       \
      unsigned int p1 = (((word) >> 16) & 0xFFu) | (((word) >> 24) << 16);  \
      atomicAdd(&acc[a1e ^ (jb + 0u)], p0);                                 \
      atomicAdd(&acc[a1e ^ (jb + 1u)], p1); }

__global__ __launch_bounds__(512) void a4row_k(const uint4* __restrict__ a3d4,
                                               const int* __restrict__ deg,
                                               const int* __restrict__ nbr,
                                               const int* __restrict__ ord,
                                               const float* __restrict__ feats,
                                               const float* __restrict__ e_w,
                                               const float* __restrict__ e_b,
                                               float* __restrict__ x0) {
    __shared__ __align__(64) unsigned int acc[NN / 2];     // 8 KB u16-packed
    __shared__ unsigned int sbase[64];
    __shared__ unsigned int wtops[64];
    int tid = threadIdx.x;
    int wv = tid >> 6, ln = tid & 63;
    int v = ord[blockIdx.x];

    {
        uint4 z = {0u, 0u, 0u, 0u};
        ((uint4*)acc)[tid] = z;
    }
    int dvv = min(deg[v], 64);
    if (tid < dvv) sbase[tid] = (unsigned int)nbr[v * 64 + tid] * 256u;
    __syncthreads();

    int tot = dvv << 8;
    for (int g = tid; g < tot; g += 512) {
        unsigned int d = (unsigned int)g & 255u;
        uint4 E = a3d4[sbase[g >> 8] + d];
        unsigned int a1e = (d << 3) | ((d >> 2) & 7u);
        DOPAIRS(E.x, 0u)
        DOPAIRS(E.y, 2u)
        DOPAIRS(E.z, 4u)
        DOPAIRS(E.w, 6u)
    }
    __syncthreads();

    // per-thread top-8 over 4 conflict-free LDS reads (8 u16 values)
    unsigned int best[8];
    #pragma unroll
    for (int q = 0; q < 8; q++) best[q] = 0u;
    #pragma unroll
    for (int m = 0; m < 4; m++) {
        unsigned int w = acc[tid + 512 * m];
        #pragma unroll
        for (int hlf = 0; hlf < 2; hlf++) {
            unsigned int val = hlf ? (w >> 16) : (w & 0xFFFFu);
            if (val > best[7]) {
                best[7] = val;
                #pragma unroll
                for (int s = 7; s > 0; s--) {
                    if (best[s] > best[s - 1]) {
                        unsigned int t2 = best[s - 1]; best[s - 1] = best[s]; best[s] = t2;
                    } else break;
                }
            }
        }
    }

    // per-wave extract of 8 maxima (shfl-only)
    unsigned int wave_val = 0u;
    #pragma unroll
    for (int r = 0; r < 8; r++) {
        unsigned int m = best[0];
        #pragma unroll
        for (int off = 32; off; off >>= 1)
            m = max(m, (unsigned int)__shfl_xor((int)m, off, 64));
        unsigned long long bb = __ballot(best[0] == m);
        int src = __ffsll(bb) - 1;
        if (ln == src) {
            #pragma unroll
            for (int s = 0; s < 7; s++) best[s] = best[s + 1];
            best[7] = 0u;
        }
        if (ln == r) wave_val = m;
    }
    if (ln < 8) wtops[wv * 8 + ln] = wave_val;
    __syncthreads();

    // wave 0: merge 64 candidates, then fused embedding
    if (wv == 0) {
        unsigned int cand = wtops[ln];
        unsigned int myv = 0u;
        #pragma unroll
        for (int r = 0; r < 8; r++) {
            unsigned int m = cand;
            #pragma unroll
            for (int off = 32; off; off >>= 1)
                m = max(m, (unsigned int)__shfl_xor((int)m, off, 64));
            unsigned long long bb = __ballot(cand == m);
            int src = __ffsll(bb) - 1;
            if (ln == src) cand = 0u;
            if (ln == r) myv = m;
        }
        int d = ln;
        float s = e_b[d];
        s += feats[v * 16 + 0]  * e_w[0 * 64 + d];
        s += feats[v * 16 + 1]  * e_w[1 * 64 + d];
        s += feats[v * 16 + 2]  * e_w[2 * 64 + d];
        s += feats[v * 16 + 3]  * e_w[3 * 64 + d];
        #pragma unroll
        for (int j = 0; j < 8; j++) {
            float mj = (float)(unsigned int)__shfl((int)myv, j, 64);
            s += mj * e_w[(4 + j) * 64 + d];
        }
        s += feats[v * 16 + 12] * e_w[12 * 64 + d];
        s += feats[v * 16 + 13] * e_w[13 * 64 + d];
        s += feats[v * 16 + 14] * e_w[14 * 64 + d];
        x0[(size_t)v * 64 + d] = s;
    }
}

// ---------------------------------------------------------------------------
// K5: one GNN layer, weights LDS-staged. For li==2, accumulate block column
// sums directly into out[64] via fp32 atomics.
// ---------------------------------------------------------------------------
__global__ __launch_bounds__(256) void layer_k(const float* __restrict__ xin,
                                               float* __restrict__ xout,
                                               const float* __restrict__ w1,
                                               const float* __restrict__ b1,
                                               const float* __restrict__ w2,
                                               const float* __restrict__ b2,
                                               const float* __restrict__ eps,
                                               const int* __restrict__ nbr,
                                               const int* __restrict__ deg,
                                               float* __restrict__ out,
                                               int li) {
    __shared__ float wL[4096];                // 16 KB, reused for w1 then w2
    __shared__ float h[4][64], t[4][64];
    int tid = threadIdx.x;
    int wv = tid >> 6, d = tid & 63;
    int v = blockIdx.x * 4 + wv;

    // stage w1 (coalesced float4)
    {
        const float4* src = (const float4*)(w1 + li * 4096);
        #pragma unroll
        for (int i = 0; i < 4; i++) ((float4*)wL)[tid + 256 * i] = src[tid + 256 * i];
    }

    float xv = xin[(size_t)v * 64 + d];
    int dv = min(deg[v], 64);
    const int* nl = nbr + v * 64;
    float agg = 0.f;
    int j = 0;
    for (; j + 4 <= dv; j += 4) {
        int n0 = nl[j], n1 = nl[j + 1], n2 = nl[j + 2], n3 = nl[j + 3];
        float a0 = xin[(size_t)n0 * 64 + d];
        float a1 = xin[(size_t)n1 * 64 + d];
        float a2v = xin[(size_t)n2 * 64 + d];
        float a3 = xin[(size_t)n3 * 64 + d];
        agg += (a0 + a1) + (a2v + a3);
    }
    for (; j < dv; j++) agg += xin[(size_t)nl[j] * 64 + d];
    float hv = (1.0f + eps[li]) * xv + agg;
    h[wv][d] = hv;
    __syncthreads();

    float s = b1[li * 64 + d];
    #pragma unroll 8
    for (int k = 0; k < 64; k++) s += h[wv][k] * wL[k * 64 + d];
    s = fmaxf(s, 0.f);
    t[wv][d] = s;
    __syncthreads();

    // stage w2 (reuse wL)
    {
        const float4* src = (const float4*)(w2 + li * 4096);
        #pragma unroll
        for (int i = 0; i < 4; i++) ((float4*)wL)[tid + 256 * i] = src[tid + 256 * i];
    }
    __syncthreads();

    float o = b2[li * 64 + d];
    #pragma unroll 8
    for (int k = 0; k < 64; k++) o += t[wv][k] * wL[k * 64 + d];
    if (li == 2) {
        h[wv][d] = o;
        __syncthreads();
        if (wv == 0)
            atomicAdd(&out[d], (h[0][d] + h[1][d]) + (h[2][d] + h[3][d]));
    } else {
        xout[(size_t)v * 64 + d] = o;
    }
}

// ---------------------------------------------------------------------------
extern "C" void kernel_launch(void* const* d_in, const int* in_sizes, int n_in,
                              void* d_out, int out_size, void* d_ws, size_t ws_size,
                              hipStream_t stream) {
    const float* adj = (const float*)d_in[0];
    const float* e_w = (const float*)d_in[1];
    const float* e_b = (const float*)d_in[2];
    const float* w1  = (const float*)d_in[3];
    const float* b1  = (const float*)d_in[4];
    const float* w2  = (const float*)d_in[5];
    const float* b2  = (const float*)d_in[6];
    const float* eps = (const float*)d_in[7];
    float* out = (float*)d_out;

    char* ws = (char*)d_ws;
    unsigned int*       a3d     = (unsigned int*)(ws);                  // 16 MB dense u8 a3
    int*                nbr     = (int*)(ws + 25165824);                // 1 MB
    int*                deg     = (int*)(ws + 26214400);                // 16 KB
    float*              feats   = (float*)(ws + 26247168);              // 256 KB
    float*              x0      = (float*)(ws + 26509312);              // 1 MB
    float*              x1      = (float*)(ws + 27557888);              // 1 MB
    unsigned long long* abits   = (unsigned long long*)(ws + 28868608); // 2 MB
    int*                ord     = (int*)(ws + 30969856);                // 16 KB

    hipMemsetAsync(out, 0, 64 * sizeof(float), stream);
    scan_k<<<1024, 256, 0, stream>>>(adj, nbr, deg, abits, feats);
    cra2_k<<<5120, 256, 0, stream>>>(abits, nbr, deg, a3d, feats);
    order_k<<<1, 1024, 0, stream>>>(deg, ord);
    a4row_k<<<4096, 512, 0, stream>>>((const uint4*)a3d, deg, nbr, ord, feats, e_w, e_b, x0);
    layer_k<<<1024, 256, 0, stream>>>(x0, x1, w1, b1, w2, b2, eps, nbr, deg, out, 0);
    layer_k<<<1024, 256, 0, stream>>>(x1, x0, w1, b1, w2, b2, eps, nbr, deg, out, 1);
    layer_k<<<1024, 256, 0, stream>>>(x0, x1, w1, b1, w2, b2, eps, nbr, deg, out, 2);
}

// Round 6
// 262.611 us; speedup vs baseline: 1.0943x; 1.0104x over previous
//
#include <hip/hip_runtime.h>
#include <hip/hip_bf16.h>
#include <stdint.h>

#define NN 4096

// Round-26: a4 = A * (a2 * A) with NIBBLE-compressed a3 (+ exact side-list).
//   a3 row = 2048 B: 256 uint2 slots, slot q = {word q, word q+256}; word w
//   holds cols [8w, 8w+8) as 4-bit base values min(val,15).
//   side[v*192 + i] = ((val-15)<<16)|col for cols with val >= 16 (~20/row,
//   mostly x in N(v) and the diagonal, where val >= deg). base+side = val.
//   a4row_k: a4row(v) = sum_{u in N(v)} a3row(u) (17 weight-1 sources),
//   u16-packed LDS accumulation (pair pidx = col>>1), swizzled address
//   a = pidx ^ ((pidx>>5)&3): per DS instruction the 64 lanes hit every
//   bank exactly twice (exact 2-way = free). Bijective -> top-8 unchanged.
//   Unpack via v_perm_b32: x = w & 0x0F0F0F0F (even cols as bytes),
//   y = (w>>4) & 0x0F0F0F0F (odd cols); pair k = perm(y,x, 0x0c[4+k]0c[k]).

// ---------------------------------------------------------------------------
// K1: scan_k — one pass over adj per row with float4 loads (16 B/lane).
// Bit layout of abits (must match cr-role reads): for element e,
//   word(e) = ((e>>8)<<2) | (e&3),  bit(e) = (e>>2)&63.
// nbr list order is scrambled vs ascending — all consumers set-order-agnostic.
// ---------------------------------------------------------------------------
__global__ __launch_bounds__(256) void scan_k(const float* __restrict__ adj,
                                              int* __restrict__ nbr,
                                              int* __restrict__ deg,
                                              unsigned long long* __restrict__ abits,
                                              float* __restrict__ feats) {
    __shared__ int nlist[4][64];
    int tid = threadIdx.x;
    int wv = tid >> 6, ln = tid & 63;
    int v = blockIdx.x * 4 + wv;
    size_t rb = (size_t)v * NN;
    int total = 0;
    unsigned long long w0 = 0;
    const float4* row4 = (const float4*)(adj + rb);
    for (int base = 0; base < NN; base += 256) {
        float4 f = row4[(base >> 2) + ln];
        int q4 = (base >> 8) << 2;
        #pragma unroll
        for (int j = 0; j < 4; j++) {
            float vj = (j == 0) ? f.x : (j == 1) ? f.y : (j == 2) ? f.z : f.w;
            unsigned long long m = __ballot(vj > 0.5f);
            if (vj > 0.5f) {
                int pos = total + __popcll(m & ((1ull << ln) - 1ull));
                if (pos < 64) nlist[wv][pos] = base + 4 * ln + j;
            }
            if (ln == q4 + j) w0 = m;
            total += __popcll(m);
        }
    }
    abits[(size_t)v * 64 + ln] = w0;
    int degL = min(total, 64);
    if (ln < degL) nbr[v * 64 + ln] = nlist[wv][ln];
    if (ln == 0) {
        deg[v] = total;
        float degf = (float)total;
        feats[v * 16 + 12] = degf;
        feats[v * 16 + 13] = degf * degf;
        feats[v * 16 + 14] = degf;           // diag(A^2) = deg (symmetric 0/1)
    }
}

// ---------------------------------------------------------------------------
// K2: cra2_k — role-split merged dispatch:
//   blocks [0, 4096):    a2 (LDS) -> source list -> a3 (LDS) -> nibble row
//                        + overflow side-list
//   blocks [4096, 5120): cr_feat from the L2-resident bitmask (4 nodes/block)
// ---------------------------------------------------------------------------
__global__ __launch_bounds__(256) void cra2_k(const unsigned long long* __restrict__ abits,
                                              const int* __restrict__ nbr,
                                              const int* __restrict__ deg,
                                              unsigned int* __restrict__ a3n,
                                              unsigned int* __restrict__ side,
                                              unsigned int* __restrict__ scnt,
                                              float* __restrict__ feats) {
    __shared__ __align__(64) unsigned int smem[NN + 132 + 640];
    int tid = threadIdx.x;
    int bid = blockIdx.x;
    int wv = tid >> 6, ln = tid & 63;

    if (bid < NN) {
        // ------------------- a2 -> a3 role -------------------
        unsigned int* acc   = smem;                     // [4096]
        int* us             = (int*)(smem + NN);        // [64]
        int* dus            = (int*)(smem + NN + 64);   // [64]
        unsigned int* wsumS = smem + NN + 128;          // [4]
        unsigned int* srcL  = smem + NN + 132;          // [640] (w<<19)|(dgu<<12)|col
        int v = bid;
        uint4 z = {0u, 0u, 0u, 0u};
        #pragma unroll
        for (int i = 0; i < 4; i++) ((uint4*)acc)[tid + 256 * i] = z;
        int dv = min(deg[v], 64);
        if (tid < dv) {
            int u = nbr[v * 64 + tid];
            us[tid] = u;
            dus[tid] = min(deg[u], 64);
        }
        __syncthreads();
        // a2 scatter: acc[x] = a2[v][x]
        for (int p = tid; p < dv * 64; p += 256) {
            int i = p >> 6, wi = p & 63;
            if (wi < dus[i]) atomicAdd(&acc[nbr[us[i] * 64 + wi]], 1u);
        }
        __syncthreads();
        // build compact source list (col, full weight, deg(col))
        unsigned int myw[16];
        int local = 0;
        #pragma unroll
        for (int m = 0; m < 16; m++) {
            unsigned int a = acc[tid + 256 * m];
            myw[m] = a;
            local += (a != 0u);
        }
        int incl = local;
        #pragma unroll
        for (int off = 1; off < 64; off <<= 1) {
            int n = __shfl_up(incl, off, 64);
            if (ln >= off) incl += n;
        }
        if (ln == 63) wsumS[wv] = (unsigned int)incl;
        __syncthreads();
        unsigned int wpre = 0, nsrc = 0;
        #pragma unroll
        for (int q = 0; q < 4; q++) {
            unsigned int s = wsumS[q];
            if (q < wv) wpre += s;
            nsrc += s;
        }
        unsigned int pos = wpre + (unsigned int)(incl - local);
        #pragma unroll
        for (int m = 0; m < 16; m++) {
            unsigned int a = myw[m];
            if (a) {
                unsigned int col = (unsigned int)tid + 256u * m;
                unsigned int dgu = (unsigned int)min(deg[col], 64);
                if (pos < 640u) srcL[pos] = (a << 19) | (dgu << 12) | col;
                pos++;
            }
        }
        if (nsrc > 640u) nsrc = 640u;
        __syncthreads();
        // re-zero acc, then a3 scatter: acc[x] = sum_u a2[v,u]*A[u,x]
        // 2 sources per wave-instr; dgu>32 tail (P ~ 3e-5) serial on j==31.
        #pragma unroll
        for (int i = 0; i < 4; i++) ((uint4*)acc)[tid + 256 * i] = z;
        __syncthreads();
        int lim64 = (((int)nsrc + 1) >> 1) << 6;
        for (int q = tid; q < lim64; q += 256) {
            int s = ((q >> 6) << 1) | ((q >> 5) & 1);
            int j = q & 31;
            if (s < (int)nsrc) {
                unsigned int e = srcL[s];
                int dgu = (int)((e >> 12) & 0x7Fu);
                unsigned int w = e >> 19;
                const int* nru = nbr + (e & 0xFFFu) * 64;
                if (j < dgu) atomicAdd(&acc[nru[j]], w);
                if (j == 31) {
                    for (int jj = 32; jj < dgu; jj++) atomicAdd(&acc[nru[jj]], w);
                }
            }
        }
        __syncthreads();
        // nibble emit (half-interleaved uint2) + overflow side-list
        unsigned int wAn = 0, wBn = 0, ovm = 0;
        #pragma unroll
        for (int i2 = 0; i2 < 8; i2++) {
            unsigned int a = acc[8 * tid + i2];
            wAn |= min(a, 15u) << (4 * i2);
            ovm |= (a > 15u ? 1u : 0u) << i2;
        }
        #pragma unroll
        for (int i2 = 0; i2 < 8; i2++) {
            unsigned int a = acc[2048 + 8 * tid + i2];
            wBn |= min(a, 15u) << (4 * i2);
            ovm |= (a > 15u ? 1u : 0u) << (8 + i2);
        }
        {
            uint2 nw; nw.x = wAn; nw.y = wBn;
            ((uint2*)((char*)a3n + (size_t)v * 2048))[tid] = nw;
        }
        int lov = __popc(ovm);
        int inc2 = lov;
        #pragma unroll
        for (int off = 1; off < 64; off <<= 1) {
            int n = __shfl_up(inc2, off, 64);
            if (ln >= off) inc2 += n;
        }
        if (ln == 63) wsumS[wv] = (unsigned int)inc2;
        __syncthreads();
        unsigned int wpre2 = 0, totS = 0;
        #pragma unroll
        for (int q = 0; q < 4; q++) {
            unsigned int s = wsumS[q];
            if (q < wv) wpre2 += s;
            totS += s;
        }
        unsigned int pos2 = wpre2 + (unsigned int)(inc2 - lov);
        unsigned int* sideR = side + (size_t)v * 192;
        while (ovm) {
            int i2 = __ffs(ovm) - 1;
            ovm &= ovm - 1;
            unsigned int col = (i2 < 8) ? (unsigned int)(8 * tid + i2)
                                        : (unsigned int)(2048 + 8 * tid + (i2 - 8));
            unsigned int a = acc[col];
            if (pos2 < 192u) sideR[pos2] = ((a - 15u) << 16) | col;
            pos2++;
        }
        if (tid == 0) scnt[v] = min(totS, 192u);
    } else {
        // ------------------- cr role -------------------
        unsigned long long* rows = (unsigned long long*)smem;   // [4][64], 2 KB
        int* mems = (int*)(smem + 1024);                        // [4][64], 1 KB
        int v = (bid - NN) * 4 + wv;

        int dv = deg[v];
        int degL = min(dv, 64);
        int c = min(dv + 1, 64);

        int nl = (ln < degL) ? nbr[v * 64 + ln] : 0;
        int isless = (ln < degL && nl < v) ? 1 : 0;
        int pos = isless;
        #pragma unroll
        for (int off = 32; off; off >>= 1) pos += __shfl_xor(pos, off, 64);

        int mem = 0;
        if (ln < c) {
            if (ln < pos)       mem = nl;
            else if (ln == pos) mem = v;
            else                mem = nbr[v * 64 + ln - 1];
        }
        mems[wv * 64 + ln] = mem;
        __syncthreads();

        unsigned long long mask = 0ull;
        {
            const unsigned long long* rowb = abits + (size_t)mem * 64;
            for (int j = 0; j < c; j++) {
                int mj = mems[wv * 64 + j];
                unsigned long long w = rowb[((mj >> 8) << 2) | (mj & 3)];
                mask |= ((w >> ((mj >> 2) & 63)) & 1ull) << j;
            }
        }
        if (ln >= c) mask = 0ull;
        rows[wv * 64 + ln] = mask;
        __syncthreads();

        int tpart = 0;
        float epart = 0.f, wpart = 0.f;
        if (ln < c) {
            unsigned long long mm = mask;
            while (mm) {
                int j = __ffsll(mm) - 1;
                mm &= mm - 1;
                tpart += __popcll(mask & rows[wv * 64 + j]);
            }
            if (ln != pos) {
                int cn = __popcll(rows[wv * 64 + pos] & mask);
                float D2 = (float)cn + 1.0f;
                epart = D2;
                wpart = D2 * (D2 - 1.0f) * 0.5f;
            }
        }
        float es = epart, wsum2 = wpart;
        int ts = tpart;
        #pragma unroll
        for (int off = 32; off; off >>= 1) {
            es += __shfl_xor(es, off, 64);
            wsum2 += __shfl_xor(wsum2, off, 64);
            ts += __shfl_xor(ts, off, 64);
        }

        if (ln == 0) {
            float degf = (float)dv;
            float k = degf + 1.0f;
            float E = 0.5f * (es + degf);
            float W = wsum2 + degf * (degf - 1.0f) * 0.5f;
            float T = (float)ts / 6.0f;
            float f3 = T;
            float f2 = W - 3.0f * T;
            float f1 = E * (k - 2.0f) - 2.0f * f2 - 3.0f * f3;
            float tot2 = k * (k - 1.0f) * (k - 2.0f) / 6.0f;
            float f0 = tot2 - f1 - f2 - f3;
            if (k < 3.0f) { f0 = f1 = f2 = f3 = 0.f; }
            float s = f0 + f1 + f2 + f3 + 1e-10f;
            feats[v * 16 + 0] = f0 / s;
            feats[v * 16 + 1] = f1 / s;
            feats[v * 16 + 2] = f2 / s;
            feats[v * 16 + 3] = f3 / s;
        }
    }
}

// ---------------------------------------------------------------------------
// K3: order_k — counting sort of rows by deg DESCENDING (a4 work ∝ deg).
// ---------------------------------------------------------------------------
__global__ __launch_bounds__(1024) void order_k(const int* __restrict__ deg,
                                                int* __restrict__ ord) {
    __shared__ unsigned int bcnt[192];
    __shared__ unsigned int bbase[192];
    int tid = threadIdx.x;
    if (tid < 192) bcnt[tid] = 0u;
    __syncthreads();
    unsigned char myk[4];
    #pragma unroll
    for (int j = 0; j < 4; j++) {
        int v = tid * 4 + j;
        myk[j] = (unsigned char)min(deg[v], 191);
        atomicAdd(&bcnt[myk[j]], 1u);
    }
    __syncthreads();
    if (tid == 0) {
        unsigned int run = 0;
        for (int b = 191; b >= 0; b--) { bbase[b] = run; run += bcnt[b]; }
    }
    __syncthreads();
    #pragma unroll
    for (int j = 0; j < 4; j++) {
        int v = tid * 4 + j;
        unsigned int p = atomicAdd(&bbase[myk[j]], 1u);
        ord[p] = v;
    }
}

// ---------------------------------------------------------------------------
// K4: fused a4-row (nibble a3 + side-list) + top-8 + embedding.
// Phase 1: base nibbles, v_perm unpack, exact 2-way banked u16-pair atomics.
// Phase 2: side entries (few) into the same swizzled accumulator.
// ---------------------------------------------------------------------------
#define DONIB(w, a1e) \
    { unsigned int x_ = (w) & 0x0F0F0F0Fu;                                      \
      unsigned int y_ = ((w) >> 4) & 0x0F0F0F0Fu;                               \
      atomicAdd(&acc[(a1e) ^ 0u], __builtin_amdgcn_perm(y_, x_, 0x0c040c00u));  \
      atomicAdd(&acc[(a1e) ^ 1u], __builtin_amdgcn_perm(y_, x_, 0x0c050c01u));  \
      atomicAdd(&acc[(a1e) ^ 2u], __builtin_amdgcn_perm(y_, x_, 0x0c060c02u));  \
      atomicAdd(&acc[(a1e) ^ 3u], __builtin_amdgcn_perm(y_, x_, 0x0c070c03u)); }

__global__ __launch_bounds__(512) void a4row_k(const uint2* __restrict__ a3n2,
                                               const unsigned int* __restrict__ side,
                                               const unsigned int* __restrict__ scnt,
                                               const int* __restrict__ deg,
                                               const int* __restrict__ nbr,
                                               const int* __restrict__ ord,
                                               const float* __restrict__ feats,
                                               const float* __restrict__ e_w,
                                               const float* __restrict__ e_b,
                                               float* __restrict__ x0) {
    __shared__ __align__(64) unsigned int acc[NN / 2];     // 8 KB u16-packed
    __shared__ unsigned int sbase[64];                     // neighbor row ids
    __shared__ unsigned int sS[64];                        // side counts
    __shared__ unsigned int wtops[64];
    int tid = threadIdx.x;
    int wv = tid >> 6, ln = tid & 63;
    int v = ord[blockIdx.x];

    {
        uint4 z = {0u, 0u, 0u, 0u};
        ((uint4*)acc)[tid] = z;
    }
    int dvv = min(deg[v], 64);
    if (tid < dvv) {
        unsigned int u = (unsigned int)nbr[v * 64 + tid];
        sbase[tid] = u;
        sS[tid] = scnt[u];
    }
    __syncthreads();

    // phase 1: base nibbles. slot q of source u = words {q, q+256}.
    int tot1 = dvv << 8;
    for (int g = tid; g < tot1; g += 512) {
        unsigned int q = (unsigned int)g & 255u;
        uint2 W = a3n2[sbase[g >> 8] * 256u + q];
        unsigned int a1e = (q << 2) | ((q >> 3) & 3u);
        DONIB(W.x, a1e)
        DONIB(W.y, a1e + 1024u)
    }
    // phase 2: side entries (atomics into same acc; no barrier needed)
    for (int i = wv; i < dvv; i += 8) {
        int ns = (int)sS[i];
        const unsigned int* sp = side + (size_t)sbase[i] * 192;
        for (int g2 = ln; g2 < ns; g2 += 64) {
            unsigned int e = sp[g2];
            unsigned int col = e & 0xFFFu;
            unsigned int w = e >> 16;
            unsigned int pidx = col >> 1;
            unsigned int ad = pidx ^ ((pidx >> 5) & 3u);
            atomicAdd(&acc[ad], w << ((col & 1u) << 4));
        }
    }
    __syncthreads();

    // per-thread top-8 over 4 conflict-free LDS reads (8 u16 values)
    unsigned int best[8];
    #pragma unroll
    for (int q = 0; q < 8; q++) best[q] = 0u;
    #pragma unroll
    for (int m = 0; m < 4; m++) {
        unsigned int w = acc[tid + 512 * m];
        #pragma unroll
        for (int hlf = 0; hlf < 2; hlf++) {
            unsigned int val = hlf ? (w >> 16) : (w & 0xFFFFu);
            if (val > best[7]) {
                best[7] = val;
                #pragma unroll
                for (int s = 7; s > 0; s--) {
                    if (best[s] > best[s - 1]) {
                        unsigned int t2 = best[s - 1]; best[s - 1] = best[s]; best[s] = t2;
                    } else break;
                }
            }
        }
    }

    // per-wave extract of 8 maxima (shfl-only)
    unsigned int wave_val = 0u;
    #pragma unroll
    for (int r = 0; r < 8; r++) {
        unsigned int m = best[0];
        #pragma unroll
        for (int off = 32; off; off >>= 1)
            m = max(m, (unsigned int)__shfl_xor((int)m, off, 64));
        unsigned long long bb = __ballot(best[0] == m);
        int src = __ffsll(bb) - 1;
        if (ln == src) {
            #pragma unroll
            for (int s = 0; s < 7; s++) best[s] = best[s + 1];
            best[7] = 0u;
        }
        if (ln == r) wave_val = m;
    }
    if (ln < 8) wtops[wv * 8 + ln] = wave_val;
    __syncthreads();

    // wave 0: merge 64 candidates, then fused embedding
    if (wv == 0) {
        unsigned int cand = wtops[ln];
        unsigned int myv = 0u;
        #pragma unroll
        for (int r = 0; r < 8; r++) {
            unsigned int m = cand;
            #pragma unroll
            for (int off = 32; off; off >>= 1)
                m = max(m, (unsigned int)__shfl_xor((int)m, off, 64));
            unsigned long long bb = __ballot(cand == m);
            int src = __ffsll(bb) - 1;
            if (ln == src) cand = 0u;
            if (ln == r) myv = m;
        }
        int d = ln;
        float s = e_b[d];
        s += feats[v * 16 + 0]  * e_w[0 * 64 + d];
        s += feats[v * 16 + 1]  * e_w[1 * 64 + d];
        s += feats[v * 16 + 2]  * e_w[2 * 64 + d];
        s += feats[v * 16 + 3]  * e_w[3 * 64 + d];
        #pragma unroll
        for (int j = 0; j < 8; j++) {
            float mj = (float)(unsigned int)__shfl((int)myv, j, 64);
            s += mj * e_w[(4 + j) * 64 + d];
        }
        s += feats[v * 16 + 12] * e_w[12 * 64 + d];
        s += feats[v * 16 + 13] * e_w[13 * 64 + d];
        s += feats[v * 16 + 14] * e_w[14 * 64 + d];
        x0[(size_t)v * 64 + d] = s;
    }
}

// ---------------------------------------------------------------------------
// K5: one GNN layer, weights LDS-staged. For li==2, accumulate block column
// sums directly into out[64] via fp32 atomics.
// ---------------------------------------------------------------------------
__global__ __launch_bounds__(256) void layer_k(const float* __restrict__ xin,
                                               float* __restrict__ xout,
                                               const float* __restrict__ w1,
                                               const float* __restrict__ b1,
                                               const float* __restrict__ w2,
                                               const float* __restrict__ b2,
                                               const float* __restrict__ eps,
                                               const int* __restrict__ nbr,
                                               const int* __restrict__ deg,
                                               float* __restrict__ out,
                                               int li) {
    __shared__ float wL[4096];                // 16 KB, reused for w1 then w2
    __shared__ float h[4][64], t[4][64];
    int tid = threadIdx.x;
    int wv = tid >> 6, d = tid & 63;
    int v = blockIdx.x * 4 + wv;

    // stage w1 (coalesced float4)
    {
        const float4* src = (const float4*)(w1 + li * 4096);
        #pragma unroll
        for (int i = 0; i < 4; i++) ((float4*)wL)[tid + 256 * i] = src[tid + 256 * i];
    }

    float xv = xin[(size_t)v * 64 + d];
    int dv = min(deg[v], 64);
    const int* nl = nbr + v * 64;
    float agg = 0.f;
    int j = 0;
    for (; j + 4 <= dv; j += 4) {
        int n0 = nl[j], n1 = nl[j + 1], n2 = nl[j + 2], n3 = nl[j + 3];
        float a0 = xin[(size_t)n0 * 64 + d];
        float a1 = xin[(size_t)n1 * 64 + d];
        float a2v = xin[(size_t)n2 * 64 + d];
        float a3 = xin[(size_t)n3 * 64 + d];
        agg += (a0 + a1) + (a2v + a3);
    }
    for (; j < dv; j++) agg += xin[(size_t)nl[j] * 64 + d];
    float hv = (1.0f + eps[li]) * xv + agg;
    h[wv][d] = hv;
    __syncthreads();

    float s = b1[li * 64 + d];
    #pragma unroll 8
    for (int k = 0; k < 64; k++) s += h[wv][k] * wL[k * 64 + d];
    s = fmaxf(s, 0.f);
    t[wv][d] = s;
    __syncthreads();

    // stage w2 (reuse wL)
    {
        const float4* src = (const float4*)(w2 + li * 4096);
        #pragma unroll
        for (int i = 0; i < 4; i++) ((float4*)wL)[tid + 256 * i] = src[tid + 256 * i];
    }
    __syncthreads();

    float o = b2[li * 64 + d];
    #pragma unroll 8
    for (int k = 0; k < 64; k++) o += t[wv][k] * wL[k * 64 + d];
    if (li == 2) {
        h[wv][d] = o;
        __syncthreads();
        if (wv == 0)
            atomicAdd(&out[d], (h[0][d] + h[1][d]) + (h[2][d] + h[3][d]));
    } else {
        xout[(size_t)v * 64 + d] = o;
    }
}

// ---------------------------------------------------------------------------
extern "C" void kernel_launch(void* const* d_in, const int* in_sizes, int n_in,
                              void* d_out, int out_size, void* d_ws, size_t ws_size,
                              hipStream_t stream) {
    const float* adj = (const float*)d_in[0];
    const float* e_w = (const float*)d_in[1];
    const float* e_b = (const float*)d_in[2];
    const float* w1  = (const float*)d_in[3];
    const float* b1  = (const float*)d_in[4];
    const float* w2  = (const float*)d_in[5];
    const float* b2  = (const float*)d_in[6];
    const float* eps = (const float*)d_in[7];
    float* out = (float*)d_out;

    char* ws = (char*)d_ws;
    unsigned int*       a3n     = (unsigned int*)(ws);                  // 8 MB nibble a3
    unsigned int*       side    = (unsigned int*)(ws + 8388608);        // 3 MB side-list
    unsigned int*       scnt    = (unsigned int*)(ws + 11534336);       // 16 KB
    int*                nbr     = (int*)(ws + 25165824);                // 1 MB
    int*                deg     = (int*)(ws + 26214400);                // 16 KB
    float*              feats   = (float*)(ws + 26247168);              // 256 KB
    float*              x0      = (float*)(ws + 26509312);              // 1 MB
    float*              x1      = (float*)(ws + 27557888);              // 1 MB
    unsigned long long* abits   = (unsigned long long*)(ws + 28868608); // 2 MB
    int*                ord     = (int*)(ws + 30969856);                // 16 KB

    hipMemsetAsync(out, 0, 64 * sizeof(float), stream);
    scan_k<<<1024, 256, 0, stream>>>(adj, nbr, deg, abits, feats);
    cra2_k<<<5120, 256, 0, stream>>>(abits, nbr, deg, a3n, side, scnt, feats);
    order_k<<<1, 1024, 0, stream>>>(deg, ord);
    a4row_k<<<4096, 512, 0, stream>>>((const uint2*)a3n, side, scnt, deg, nbr, ord, feats, e_w, e_b, x0);
    layer_k<<<1024, 256, 0, stream>>>(x0, x1, w1, b1, w2, b2, eps, nbr, deg, out, 0);
    layer_k<<<1024, 256, 0, stream>>>(x1, x0, w1, b1, w2, b2, eps, nbr, deg, out, 1);
    layer_k<<<1024, 256, 0, stream>>>(x0, x1, w1, b1, w2, b2, eps, nbr, deg, out, 2);
}

// Round 7
// 259.728 us; speedup vs baseline: 1.1065x; 1.0111x over previous
//
#include <hip/hip_runtime.h>
#include <hip/hip_bf16.h>
#include <stdint.h>

#define NN 4096

// Round-27: a4 = A * (a2 * A); a3 stored as LINEAR nibble rows (+ side-list),
// a4row via REGISTER-GATHER (owner-columns), no LDS scatter for the base.
//   a3 row = 512 u32 words (2048 B); word w holds cols [8w,8w+8) as 4-bit
//   base values min(val,15). side[v*192+i] = ((val-15)<<16)|col for val>=16
//   (~20/row). base+side = val exactly.
//   a4row_k: thread t owns cols [8t,8t+8) (word t). Per source u: one
//   coalesced u32 load, u8-lane adds aE/aO (safe: 16 srcs x 15 = 240 <= 255),
//   spill to u16 regs every 16 sources. Side entries scattered into a u32
//   LDS array (few hundred/block) and merged at the end. Top-8 from regs.

// ---------------------------------------------------------------------------
// K1: scan_k — one pass over adj per row with float4 loads (16 B/lane).
// Bit layout of abits (must match cr-role reads): for element e,
//   word(e) = ((e>>8)<<2) | (e&3),  bit(e) = (e>>2)&63.
// nbr list order is scrambled vs ascending — all consumers set-order-agnostic.
// ---------------------------------------------------------------------------
__global__ __launch_bounds__(256) void scan_k(const float* __restrict__ adj,
                                              int* __restrict__ nbr,
                                              int* __restrict__ deg,
                                              unsigned long long* __restrict__ abits,
                                              float* __restrict__ feats) {
    __shared__ int nlist[4][64];
    int tid = threadIdx.x;
    int wv = tid >> 6, ln = tid & 63;
    int v = blockIdx.x * 4 + wv;
    size_t rb = (size_t)v * NN;
    int total = 0;
    unsigned long long w0 = 0;
    const float4* row4 = (const float4*)(adj + rb);
    for (int base = 0; base < NN; base += 256) {
        float4 f = row4[(base >> 2) + ln];
        int q4 = (base >> 8) << 2;
        #pragma unroll
        for (int j = 0; j < 4; j++) {
            float vj = (j == 0) ? f.x : (j == 1) ? f.y : (j == 2) ? f.z : f.w;
            unsigned long long m = __ballot(vj > 0.5f);
            if (vj > 0.5f) {
                int pos = total + __popcll(m & ((1ull << ln) - 1ull));
                if (pos < 64) nlist[wv][pos] = base + 4 * ln + j;
            }
            if (ln == q4 + j) w0 = m;
            total += __popcll(m);
        }
    }
    abits[(size_t)v * 64 + ln] = w0;
    int degL = min(total, 64);
    if (ln < degL) nbr[v * 64 + ln] = nlist[wv][ln];
    if (ln == 0) {
        deg[v] = total;
        float degf = (float)total;
        feats[v * 16 + 12] = degf;
        feats[v * 16 + 13] = degf * degf;
        feats[v * 16 + 14] = degf;           // diag(A^2) = deg (symmetric 0/1)
    }
}

// ---------------------------------------------------------------------------
// K2: cra2_k — role-split merged dispatch:
//   blocks [0, 4096):    a2 (LDS) -> source list -> a3 (LDS) -> linear nibble
//                        row + overflow side-list
//   blocks [4096, 5120): cr_feat from the L2-resident bitmask (4 nodes/block)
// ---------------------------------------------------------------------------
__global__ __launch_bounds__(256) void cra2_k(const unsigned long long* __restrict__ abits,
                                              const int* __restrict__ nbr,
                                              const int* __restrict__ deg,
                                              unsigned int* __restrict__ a3n,
                                              unsigned int* __restrict__ side,
                                              unsigned int* __restrict__ scnt,
                                              float* __restrict__ feats) {
    __shared__ __align__(64) unsigned int smem[NN + 132 + 640];
    int tid = threadIdx.x;
    int bid = blockIdx.x;
    int wv = tid >> 6, ln = tid & 63;

    if (bid < NN) {
        // ------------------- a2 -> a3 role -------------------
        unsigned int* acc   = smem;                     // [4096]
        int* us             = (int*)(smem + NN);        // [64]
        int* dus            = (int*)(smem + NN + 64);   // [64]
        unsigned int* wsumS = smem + NN + 128;          // [4]
        unsigned int* srcL  = smem + NN + 132;          // [640] (w<<19)|(dgu<<12)|col
        int v = bid;
        uint4 z = {0u, 0u, 0u, 0u};
        #pragma unroll
        for (int i = 0; i < 4; i++) ((uint4*)acc)[tid + 256 * i] = z;
        int dv = min(deg[v], 64);
        if (tid < dv) {
            int u = nbr[v * 64 + tid];
            us[tid] = u;
            dus[tid] = min(deg[u], 64);
        }
        __syncthreads();
        // a2 scatter: acc[x] = a2[v][x]
        for (int p = tid; p < dv * 64; p += 256) {
            int i = p >> 6, wi = p & 63;
            if (wi < dus[i]) atomicAdd(&acc[nbr[us[i] * 64 + wi]], 1u);
        }
        __syncthreads();
        // build compact source list (col, full weight, deg(col))
        unsigned int myw[16];
        int local = 0;
        #pragma unroll
        for (int m = 0; m < 16; m++) {
            unsigned int a = acc[tid + 256 * m];
            myw[m] = a;
            local += (a != 0u);
        }
        int incl = local;
        #pragma unroll
        for (int off = 1; off < 64; off <<= 1) {
            int n = __shfl_up(incl, off, 64);
            if (ln >= off) incl += n;
        }
        if (ln == 63) wsumS[wv] = (unsigned int)incl;
        __syncthreads();
        unsigned int wpre = 0, nsrc = 0;
        #pragma unroll
        for (int q = 0; q < 4; q++) {
            unsigned int s = wsumS[q];
            if (q < wv) wpre += s;
            nsrc += s;
        }
        unsigned int pos = wpre + (unsigned int)(incl - local);
        #pragma unroll
        for (int m = 0; m < 16; m++) {
            unsigned int a = myw[m];
            if (a) {
                unsigned int col = (unsigned int)tid + 256u * m;
                unsigned int dgu = (unsigned int)min(deg[col], 64);
                if (pos < 640u) srcL[pos] = (a << 19) | (dgu << 12) | col;
                pos++;
            }
        }
        if (nsrc > 640u) nsrc = 640u;
        __syncthreads();
        // re-zero acc, then a3 scatter: acc[x] = sum_u a2[v,u]*A[u,x]
        // 2 sources per wave-instr; dgu>32 tail (P ~ 3e-5) serial on j==31.
        #pragma unroll
        for (int i = 0; i < 4; i++) ((uint4*)acc)[tid + 256 * i] = z;
        __syncthreads();
        int lim64 = (((int)nsrc + 1) >> 1) << 6;
        for (int q = tid; q < lim64; q += 256) {
            int s = ((q >> 6) << 1) | ((q >> 5) & 1);
            int j = q & 31;
            if (s < (int)nsrc) {
                unsigned int e = srcL[s];
                int dgu = (int)((e >> 12) & 0x7Fu);
                unsigned int w = e >> 19;
                const int* nru = nbr + (e & 0xFFFu) * 64;
                if (j < dgu) atomicAdd(&acc[nru[j]], w);
                if (j == 31) {
                    for (int jj = 32; jj < dgu; jj++) atomicAdd(&acc[nru[jj]], w);
                }
            }
        }
        __syncthreads();
        // linear nibble emit + overflow side-list (col = 16*tid + i2)
        unsigned int wAn = 0, wBn = 0, ovm = 0;
        #pragma unroll
        for (int i2 = 0; i2 < 8; i2++) {
            unsigned int a = acc[16 * tid + i2];
            wAn |= min(a, 15u) << (4 * i2);
            ovm |= (a > 15u ? 1u : 0u) << i2;
        }
        #pragma unroll
        for (int i2 = 0; i2 < 8; i2++) {
            unsigned int a = acc[16 * tid + 8 + i2];
            wBn |= min(a, 15u) << (4 * i2);
            ovm |= (a > 15u ? 1u : 0u) << (8 + i2);
        }
        {
            uint2 nw; nw.x = wAn; nw.y = wBn;
            ((uint2*)(a3n + (size_t)v * 512))[tid] = nw;
        }
        int lov = __popc(ovm);
        int inc2 = lov;
        #pragma unroll
        for (int off = 1; off < 64; off <<= 1) {
            int n = __shfl_up(inc2, off, 64);
            if (ln >= off) inc2 += n;
        }
        if (ln == 63) wsumS[wv] = (unsigned int)inc2;
        __syncthreads();
        unsigned int wpre2 = 0, totS = 0;
        #pragma unroll
        for (int q = 0; q < 4; q++) {
            unsigned int s = wsumS[q];
            if (q < wv) wpre2 += s;
            totS += s;
        }
        unsigned int pos2 = wpre2 + (unsigned int)(inc2 - lov);
        unsigned int* sideR = side + (size_t)v * 192;
        while (ovm) {
            int i2 = __ffs(ovm) - 1;
            ovm &= ovm - 1;
            unsigned int col = (unsigned int)(16 * tid + i2);
            unsigned int a = acc[col];
            if (pos2 < 192u) sideR[pos2] = ((a - 15u) << 16) | col;
            pos2++;
        }
        if (tid == 0) scnt[v] = min(totS, 192u);
    } else {
        // ------------------- cr role -------------------
        unsigned long long* rows = (unsigned long long*)smem;   // [4][64], 2 KB
        int* mems = (int*)(smem + 1024);                        // [4][64], 1 KB
        int v = (bid - NN) * 4 + wv;

        int dv = deg[v];
        int degL = min(dv, 64);
        int c = min(dv + 1, 64);

        int nl = (ln < degL) ? nbr[v * 64 + ln] : 0;
        int isless = (ln < degL && nl < v) ? 1 : 0;
        int pos = isless;
        #pragma unroll
        for (int off = 32; off; off >>= 1) pos += __shfl_xor(pos, off, 64);

        int mem = 0;
        if (ln < c) {
            if (ln < pos)       mem = nl;
            else if (ln == pos) mem = v;
            else                mem = nbr[v * 64 + ln - 1];
        }
        mems[wv * 64 + ln] = mem;
        __syncthreads();

        unsigned long long mask = 0ull;
        {
            const unsigned long long* rowb = abits + (size_t)mem * 64;
            for (int j = 0; j < c; j++) {
                int mj = mems[wv * 64 + j];
                unsigned long long w = rowb[((mj >> 8) << 2) | (mj & 3)];
                mask |= ((w >> ((mj >> 2) & 63)) & 1ull) << j;
            }
        }
        if (ln >= c) mask = 0ull;
        rows[wv * 64 + ln] = mask;
        __syncthreads();

        int tpart = 0;
        float epart = 0.f, wpart = 0.f;
        if (ln < c) {
            unsigned long long mm = mask;
            while (mm) {
                int j = __ffsll(mm) - 1;
                mm &= mm - 1;
                tpart += __popcll(mask & rows[wv * 64 + j]);
            }
            if (ln != pos) {
                int cn = __popcll(rows[wv * 64 + pos] & mask);
                float D2 = (float)cn + 1.0f;
                epart = D2;
                wpart = D2 * (D2 - 1.0f) * 0.5f;
            }
        }
        float es = epart, wsum2 = wpart;
        int ts = tpart;
        #pragma unroll
        for (int off = 32; off; off >>= 1) {
            es += __shfl_xor(es, off, 64);
            wsum2 += __shfl_xor(wsum2, off, 64);
            ts += __shfl_xor(ts, off, 64);
        }

        if (ln == 0) {
            float degf = (float)dv;
            float k = degf + 1.0f;
            float E = 0.5f * (es + degf);
            float W = wsum2 + degf * (degf - 1.0f) * 0.5f;
            float T = (float)ts / 6.0f;
            float f3 = T;
            float f2 = W - 3.0f * T;
            float f1 = E * (k - 2.0f) - 2.0f * f2 - 3.0f * f3;
            float tot2 = k * (k - 1.0f) * (k - 2.0f) / 6.0f;
            float f0 = tot2 - f1 - f2 - f3;
            if (k < 3.0f) { f0 = f1 = f2 = f3 = 0.f; }
            float s = f0 + f1 + f2 + f3 + 1e-10f;
            feats[v * 16 + 0] = f0 / s;
            feats[v * 16 + 1] = f1 / s;
            feats[v * 16 + 2] = f2 / s;
            feats[v * 16 + 3] = f3 / s;
        }
    }
}

// ---------------------------------------------------------------------------
// K3: order_k — counting sort of rows by deg DESCENDING (a4 work ∝ deg).
// ---------------------------------------------------------------------------
__global__ __launch_bounds__(1024) void order_k(const int* __restrict__ deg,
                                                int* __restrict__ ord) {
    __shared__ unsigned int bcnt[192];
    __shared__ unsigned int bbase[192];
    int tid = threadIdx.x;
    if (tid < 192) bcnt[tid] = 0u;
    __syncthreads();
    unsigned char myk[4];
    #pragma unroll
    for (int j = 0; j < 4; j++) {
        int v = tid * 4 + j;
        myk[j] = (unsigned char)min(deg[v], 191);
        atomicAdd(&bcnt[myk[j]], 1u);
    }
    __syncthreads();
    if (tid == 0) {
        unsigned int run = 0;
        for (int b = 191; b >= 0; b--) { bbase[b] = run; run += bcnt[b]; }
    }
    __syncthreads();
    #pragma unroll
    for (int j = 0; j < 4; j++) {
        int v = tid * 4 + j;
        unsigned int p = atomicAdd(&bbase[myk[j]], 1u);
        ord[p] = v;
    }
}

// ---------------------------------------------------------------------------
// K4: fused a4-row (register-gather over linear nibble a3 + side-list) +
// top-8 + embedding. Thread t owns cols [8t, 8t+8): per source one coalesced
// u32 load, u8-lane accumulate (aE/aO), u16 spill every 16 sources. Side
// entries scattered into u32 LDS (few hundred), merged at end.
// ---------------------------------------------------------------------------
__global__ __launch_bounds__(512) void a4row_k(const unsigned int* __restrict__ a3n,
                                               const unsigned int* __restrict__ side,
                                               const unsigned int* __restrict__ scnt,
                                               const int* __restrict__ deg,
                                               const int* __restrict__ nbr,
                                               const int* __restrict__ ord,
                                               const float* __restrict__ feats,
                                               const float* __restrict__ e_w,
                                               const float* __restrict__ e_b,
                                               float* __restrict__ x0) {
    __shared__ unsigned int sacc[NN];        // 16 KB u32 side accumulator
    __shared__ unsigned int sbase[64];       // u*512 (word base of a3 row)
    __shared__ unsigned int sbs[64];         // u*192 (side base)
    __shared__ unsigned int sS[64];          // side counts
    __shared__ unsigned int wtops[64];
    int tid = threadIdx.x;
    int wv = tid >> 6, ln = tid & 63;
    int v = ord[blockIdx.x];

    {
        uint4 z = {0u, 0u, 0u, 0u};
        ((uint4*)sacc)[tid] = z;
        ((uint4*)sacc)[tid + 512] = z;
    }
    int dvv = min(deg[v], 64);
    if (tid < dvv) {
        unsigned int u = (unsigned int)nbr[v * 64 + tid];
        sbase[tid] = u * 512u;
        sbs[tid]   = u * 192u;
        sS[tid]    = scnt[u];
    }
    __syncthreads();

    // side scatter (few hundred entries; hides under the base loop)
    for (int i = wv; i < dvv; i += 8) {
        int ns = (int)sS[i];
        const unsigned int* sp = side + sbs[i];
        for (int g2 = ln; g2 < ns; g2 += 64) {
            unsigned int e = sp[g2];
            atomicAdd(&sacc[e & 0xFFFu], e >> 16);
        }
    }

    // base: register gather-accumulate (owner-columns)
    unsigned int aE = 0, aO = 0;
    unsigned int SE0 = 0, SE1 = 0, SO0 = 0, SO1 = 0;
    for (int s0 = 0; s0 < dvv; s0 += 16) {
        int se = min(s0 + 16, dvv);
        for (int s = s0; s < se; s++) {
            unsigned int w = a3n[sbase[s] + (unsigned int)tid];
            aE += w & 0x0F0F0F0Fu;
            aO += (w >> 4) & 0x0F0F0F0Fu;
        }
        SE0 += __builtin_amdgcn_perm(0u, aE, 0x0c010c00u);   // {aE.b0, aE.b1} u16
        SE1 += __builtin_amdgcn_perm(0u, aE, 0x0c030c02u);   // {aE.b2, aE.b3}
        SO0 += __builtin_amdgcn_perm(0u, aO, 0x0c010c00u);
        SO1 += __builtin_amdgcn_perm(0u, aO, 0x0c030c02u);
        aE = 0; aO = 0;
    }
    __syncthreads();

    // merge side sums (cols 8t..8t+7) with register base sums
    uint4 s03 = ((uint4*)sacc)[2 * tid];
    uint4 s47 = ((uint4*)sacc)[2 * tid + 1];
    unsigned int vv[8];
    vv[0] = (SE0 & 0xFFFFu) + s03.x;
    vv[1] = (SO0 & 0xFFFFu) + s03.y;
    vv[2] = (SE0 >> 16)     + s03.z;
    vv[3] = (SO0 >> 16)     + s03.w;
    vv[4] = (SE1 & 0xFFFFu) + s47.x;
    vv[5] = (SO1 & 0xFFFFu) + s47.y;
    vv[6] = (SE1 >> 16)     + s47.z;
    vv[7] = (SO1 >> 16)     + s47.w;

    // per-thread top-8 over the 8 owned columns
    unsigned int best[8];
    #pragma unroll
    for (int q = 0; q < 8; q++) best[q] = 0u;
    #pragma unroll
    for (int m = 0; m < 8; m++) {
        unsigned int val = vv[m];
        if (val > best[7]) {
            best[7] = val;
            #pragma unroll
            for (int s = 7; s > 0; s--) {
                if (best[s] > best[s - 1]) {
                    unsigned int t2 = best[s - 1]; best[s - 1] = best[s]; best[s] = t2;
                } else break;
            }
        }
    }

    // per-wave extract of 8 maxima (shfl-only)
    unsigned int wave_val = 0u;
    #pragma unroll
    for (int r = 0; r < 8; r++) {
        unsigned int m = best[0];
        #pragma unroll
        for (int off = 32; off; off >>= 1)
            m = max(m, (unsigned int)__shfl_xor((int)m, off, 64));
        unsigned long long bb = __ballot(best[0] == m);
        int src = __ffsll(bb) - 1;
        if (ln == src) {
            #pragma unroll
            for (int s = 0; s < 7; s++) best[s] = best[s + 1];
            best[7] = 0u;
        }
        if (ln == r) wave_val = m;
    }
    if (ln < 8) wtops[wv * 8 + ln] = wave_val;
    __syncthreads();

    // wave 0: merge 64 candidates, then fused embedding
    if (wv == 0) {
        unsigned int cand = wtops[ln];
        unsigned int myv = 0u;
        #pragma unroll
        for (int r = 0; r < 8; r++) {
            unsigned int m = cand;
            #pragma unroll
            for (int off = 32; off; off >>= 1)
                m = max(m, (unsigned int)__shfl_xor((int)m, off, 64));
            unsigned long long bb = __ballot(cand == m);
            int src = __ffsll(bb) - 1;
            if (ln == src) cand = 0u;
            if (ln == r) myv = m;
        }
        int d = ln;
        float s = e_b[d];
        s += feats[v * 16 + 0]  * e_w[0 * 64 + d];
        s += feats[v * 16 + 1]  * e_w[1 * 64 + d];
        s += feats[v * 16 + 2]  * e_w[2 * 64 + d];
        s += feats[v * 16 + 3]  * e_w[3 * 64 + d];
        #pragma unroll
        for (int j = 0; j < 8; j++) {
            float mj = (float)(unsigned int)__shfl((int)myv, j, 64);
            s += mj * e_w[(4 + j) * 64 + d];
        }
        s += feats[v * 16 + 12] * e_w[12 * 64 + d];
        s += feats[v * 16 + 13] * e_w[13 * 64 + d];
        s += feats[v * 16 + 14] * e_w[14 * 64 + d];
        x0[(size_t)v * 64 + d] = s;
    }
}

// ---------------------------------------------------------------------------
// K5: one GNN layer, weights LDS-staged. For li==2, accumulate block column
// sums directly into out[64] via fp32 atomics.
// ---------------------------------------------------------------------------
__global__ __launch_bounds__(256) void layer_k(const float* __restrict__ xin,
                                               float* __restrict__ xout,
                                               const float* __restrict__ w1,
                                               const float* __restrict__ b1,
                                               const float* __restrict__ w2,
                                               const float* __restrict__ b2,
                                               const float* __restrict__ eps,
                                               const int* __restrict__ nbr,
                                               const int* __restrict__ deg,
                                               float* __restrict__ out,
                                               int li) {
    __shared__ float wL[4096];                // 16 KB, reused for w1 then w2
    __shared__ float h[4][64], t[4][64];
    int tid = threadIdx.x;
    int wv = tid >> 6, d = tid & 63;
    int v = blockIdx.x * 4 + wv;

    // stage w1 (coalesced float4)
    {
        const float4* src = (const float4*)(w1 + li * 4096);
        #pragma unroll
        for (int i = 0; i < 4; i++) ((float4*)wL)[tid + 256 * i] = src[tid + 256 * i];
    }

    float xv = xin[(size_t)v * 64 + d];
    int dv = min(deg[v], 64);
    const int* nl = nbr + v * 64;
    float agg = 0.f;
    int j = 0;
    for (; j + 4 <= dv; j += 4) {
        int n0 = nl[j], n1 = nl[j + 1], n2 = nl[j + 2], n3 = nl[j + 3];
        float a0 = xin[(size_t)n0 * 64 + d];
        float a1 = xin[(size_t)n1 * 64 + d];
        float a2v = xin[(size_t)n2 * 64 + d];
        float a3 = xin[(size_t)n3 * 64 + d];
        agg += (a0 + a1) + (a2v + a3);
    }
    for (; j < dv; j++) agg += xin[(size_t)nl[j] * 64 + d];
    float hv = (1.0f + eps[li]) * xv + agg;
    h[wv][d] = hv;
    __syncthreads();

    float s = b1[li * 64 + d];
    #pragma unroll 8
    for (int k = 0; k < 64; k++) s += h[wv][k] * wL[k * 64 + d];
    s = fmaxf(s, 0.f);
    t[wv][d] = s;
    __syncthreads();

    // stage w2 (reuse wL)
    {
        const float4* src = (const float4*)(w2 + li * 4096);
        #pragma unroll
        for (int i = 0; i < 4; i++) ((float4*)wL)[tid + 256 * i] = src[tid + 256 * i];
    }
    __syncthreads();

    float o = b2[li * 64 + d];
    #pragma unroll 8
    for (int k = 0; k < 64; k++) o += t[wv][k] * wL[k * 64 + d];
    if (li == 2) {
        h[wv][d] = o;
        __syncthreads();
        if (wv == 0)
            atomicAdd(&out[d], (h[0][d] + h[1][d]) + (h[2][d] + h[3][d]));
    } else {
        xout[(size_t)v * 64 + d] = o;
    }
}

// ---------------------------------------------------------------------------
extern "C" void kernel_launch(void* const* d_in, const int* in_sizes, int n_in,
                              void* d_out, int out_size, void* d_ws, size_t ws_size,
                              hipStream_t stream) {
    const float* adj = (const float*)d_in[0];
    const float* e_w = (const float*)d_in[1];
    const float* e_b = (const float*)d_in[2];
    const float* w1  = (const float*)d_in[3];
    const float* b1  = (const float*)d_in[4];
    const float* w2  = (const float*)d_in[5];
    const float* b2  = (const float*)d_in[6];
    const float* eps = (const float*)d_in[7];
    float* out = (float*)d_out;

    char* ws = (char*)d_ws;
    unsigned int*       a3n     = (unsigned int*)(ws);                  // 8 MB nibble a3
    unsigned int*       side    = (unsigned int*)(ws + 8388608);        // 3 MB side-list
    unsigned int*       scnt    = (unsigned int*)(ws + 11534336);       // 16 KB
    int*                nbr     = (int*)(ws + 25165824);                // 1 MB
    int*                deg     = (int*)(ws + 26214400);                // 16 KB
    float*              feats   = (float*)(ws + 26247168);              // 256 KB
    float*              x0      = (float*)(ws + 26509312);              // 1 MB
    float*              x1      = (float*)(ws + 27557888);              // 1 MB
    unsigned long long* abits   = (unsigned long long*)(ws + 28868608); // 2 MB
    int*                ord     = (int*)(ws + 30969856);                // 16 KB

    hipMemsetAsync(out, 0, 64 * sizeof(float), stream);
    scan_k<<<1024, 256, 0, stream>>>(adj, nbr, deg, abits, feats);
    cra2_k<<<5120, 256, 0, stream>>>(abits, nbr, deg, a3n, side, scnt, feats);
    order_k<<<1, 1024, 0, stream>>>(deg, ord);
    a4row_k<<<4096, 512, 0, stream>>>(a3n, side, scnt, deg, nbr, ord, feats, e_w, e_b, x0);
    layer_k<<<1024, 256, 0, stream>>>(x0, x1, w1, b1, w2, b2, eps, nbr, deg, out, 0);
    layer_k<<<1024, 256, 0, stream>>>(x1, x0, w1, b1, w2, b2, eps, nbr, deg, out, 1);
    layer_k<<<1024, 256, 0, stream>>>(x0, x1, w1, b1, w2, b2, eps, nbr, deg, out, 2);
}

// Round 8
// 255.744 us; speedup vs baseline: 1.1237x; 1.0156x over previous
//
#include <hip/hip_runtime.h>
#include <hip/hip_bf16.h>
#include <stdint.h>

#define NN 4096

// Round-28: a4 = A * (a2 * A); linear nibble a3 (+ side-list), a4row via
// register-gather. This round:
//  - top-8 max-reduces use VALU DPP (row_shr/row_bcast), not ds_swizzle:
//    the DS pipe is one shared unit per CU and the old shfl-based extraction
//    (~100 DS instrs/block) serialized across the 16 resident blocks.
//  - cra2's a3 scatter uses exact 8-source groups with cumulative-count
//    select chains (132 -> ~86 wave-iters for the same 4356 lane-adds).
//  - order_k dropped: per-block work is uniform enough (prop. to deg).

__device__ __forceinline__ unsigned int wave_umax_bcast(unsigned int v) {
    // full-wave64 max on the VALU via DPP; result broadcast via readlane.
    // bound_ctrl=1 -> out-of-range lanes read 0 (identity for unsigned max).
    int x = (int)v;                           // values <= ~65k: signed==unsigned
    x = max(x, __builtin_amdgcn_update_dpp(0, x, 0x111, 0xF, 0xF, true)); // row_shr:1
    x = max(x, __builtin_amdgcn_update_dpp(0, x, 0x112, 0xF, 0xF, true)); // row_shr:2
    x = max(x, __builtin_amdgcn_update_dpp(0, x, 0x114, 0xF, 0xF, true)); // row_shr:4
    x = max(x, __builtin_amdgcn_update_dpp(0, x, 0x118, 0xF, 0xF, true)); // row_shr:8
    x = max(x, __builtin_amdgcn_update_dpp(0, x, 0x142, 0xF, 0xF, true)); // row_bcast:15
    x = max(x, __builtin_amdgcn_update_dpp(0, x, 0x143, 0xF, 0xF, true)); // row_bcast:31
    return (unsigned int)__builtin_amdgcn_readlane(x, 63);
}

// ---------------------------------------------------------------------------
// K1: scan_k — one pass over adj per row with float4 loads (16 B/lane).
// Bit layout of abits (must match cr-role reads): for element e,
//   word(e) = ((e>>8)<<2) | (e&3),  bit(e) = (e>>2)&63.
// nbr list order is scrambled vs ascending — all consumers set-order-agnostic.
// ---------------------------------------------------------------------------
__global__ __launch_bounds__(256) void scan_k(const float* __restrict__ adj,
                                              int* __restrict__ nbr,
                                              int* __restrict__ deg,
                                              unsigned long long* __restrict__ abits,
                                              float* __restrict__ feats) {
    __shared__ int nlist[4][64];
    int tid = threadIdx.x;
    int wv = tid >> 6, ln = tid & 63;
    int v = blockIdx.x * 4 + wv;
    size_t rb = (size_t)v * NN;
    int total = 0;
    unsigned long long w0 = 0;
    const float4* row4 = (const float4*)(adj + rb);
    for (int base = 0; base < NN; base += 256) {
        float4 f = row4[(base >> 2) + ln];
        int q4 = (base >> 8) << 2;
        #pragma unroll
        for (int j = 0; j < 4; j++) {
            float vj = (j == 0) ? f.x : (j == 1) ? f.y : (j == 2) ? f.z : f.w;
            unsigned long long m = __ballot(vj > 0.5f);
            if (vj > 0.5f) {
                int pos = total + __popcll(m & ((1ull << ln) - 1ull));
                if (pos < 64) nlist[wv][pos] = base + 4 * ln + j;
            }
            if (ln == q4 + j) w0 = m;
            total += __popcll(m);
        }
    }
    abits[(size_t)v * 64 + ln] = w0;
    int degL = min(total, 64);
    if (ln < degL) nbr[v * 64 + ln] = nlist[wv][ln];
    if (ln == 0) {
        deg[v] = total;
        float degf = (float)total;
        feats[v * 16 + 12] = degf;
        feats[v * 16 + 13] = degf * degf;
        feats[v * 16 + 14] = degf;           // diag(A^2) = deg (symmetric 0/1)
    }
}

// ---------------------------------------------------------------------------
// K2: cra2_k — role-split merged dispatch:
//   blocks [0, 4096):    a2 (LDS) -> source list -> a3 (LDS, exact-packed
//                        8-group scatter) -> linear nibble row + side-list
//   blocks [4096, 5120): cr_feat from the L2-resident bitmask (4 nodes/block)
// ---------------------------------------------------------------------------
__global__ __launch_bounds__(256) void cra2_k(const unsigned long long* __restrict__ abits,
                                              const int* __restrict__ nbr,
                                              const int* __restrict__ deg,
                                              unsigned int* __restrict__ a3n,
                                              unsigned int* __restrict__ side,
                                              unsigned int* __restrict__ scnt,
                                              float* __restrict__ feats) {
    __shared__ __align__(64) unsigned int smem[NN + 132 + 648];
    int tid = threadIdx.x;
    int bid = blockIdx.x;
    int wv = tid >> 6, ln = tid & 63;

    if (bid < NN) {
        // ------------------- a2 -> a3 role -------------------
        unsigned int* acc   = smem;                     // [4096]
        int* us             = (int*)(smem + NN);        // [64]
        int* dus            = (int*)(smem + NN + 64);   // [64]
        unsigned int* wsumS = smem + NN + 128;          // [4]
        unsigned int* srcL  = smem + NN + 132;          // [648] (w<<19)|(dgu<<12)|col
        int v = bid;
        uint4 z = {0u, 0u, 0u, 0u};
        #pragma unroll
        for (int i = 0; i < 4; i++) ((uint4*)acc)[tid + 256 * i] = z;
        int dv = min(deg[v], 64);
        if (tid < dv) {
            int u = nbr[v * 64 + tid];
            us[tid] = u;
            dus[tid] = min(deg[u], 64);
        }
        __syncthreads();
        // a2 scatter: acc[x] = a2[v][x]
        for (int p = tid; p < dv * 64; p += 256) {
            int i = p >> 6, wi = p & 63;
            if (wi < dus[i]) atomicAdd(&acc[nbr[us[i] * 64 + wi]], 1u);
        }
        __syncthreads();
        // build compact source list (col, full weight, deg(col))
        unsigned int myw[16];
        int local = 0;
        #pragma unroll
        for (int m = 0; m < 16; m++) {
            unsigned int a = acc[tid + 256 * m];
            myw[m] = a;
            local += (a != 0u);
        }
        int incl = local;
        #pragma unroll
        for (int off = 1; off < 64; off <<= 1) {
            int n = __shfl_up(incl, off, 64);
            if (ln >= off) incl += n;
        }
        if (ln == 63) wsumS[wv] = (unsigned int)incl;
        __syncthreads();
        unsigned int wpre = 0, nsrc = 0;
        #pragma unroll
        for (int q = 0; q < 4; q++) {
            unsigned int s = wsumS[q];
            if (q < wv) wpre += s;
            nsrc += s;
        }
        unsigned int pos = wpre + (unsigned int)(incl - local);
        #pragma unroll
        for (int m = 0; m < 16; m++) {
            unsigned int a = myw[m];
            if (a) {
                unsigned int col = (unsigned int)tid + 256u * m;
                unsigned int dgu = (unsigned int)min(deg[col], 64);
                if (pos < 640u) srcL[pos] = (a << 19) | (dgu << 12) | col;
                pos++;
            }
        }
        if (nsrc > 640u) nsrc = 640u;
        __syncthreads();
        // re-zero acc, then a3 scatter: acc[x] = sum_u a2[v,u]*A[u,x]
        // exact-packed: 8-source groups, cumulative counts + select chain.
        #pragma unroll
        for (int i = 0; i < 4; i++) ((uint4*)acc)[tid + 256 * i] = z;
        int nsrc8 = (((int)nsrc + 7) >> 3) << 3;
        if (tid < nsrc8 - (int)nsrc) srcL[(int)nsrc + tid] = 0u;  // dgu=0 pad
        __syncthreads();
        for (int i0 = wv * 8; i0 < nsrc8; i0 += 32) {
            uint4 qa = *(const uint4*)&srcL[i0];
            uint4 qb = *(const uint4*)&srcL[i0 + 4];
            int c1 = (int)((qa.x >> 12) & 0x7Fu);
            int c2 = c1 + (int)((qa.y >> 12) & 0x7Fu);
            int c3 = c2 + (int)((qa.z >> 12) & 0x7Fu);
            int c4 = c3 + (int)((qa.w >> 12) & 0x7Fu);
            int c5 = c4 + (int)((qb.x >> 12) & 0x7Fu);
            int c6 = c5 + (int)((qb.y >> 12) & 0x7Fu);
            int c7 = c6 + (int)((qb.z >> 12) & 0x7Fu);
            int tot = c7 + (int)((qb.w >> 12) & 0x7Fu);
            unsigned int s0 = ((qa.x & 0xFFFu) * 64u)                                | (qa.x & 0xFFF80000u);
            unsigned int s1 = ((((qa.y & 0xFFFu) * 64u) - (unsigned int)c1) & 0x7FFFFu) | (qa.y & 0xFFF80000u);
            unsigned int s2 = ((((qa.z & 0xFFFu) * 64u) - (unsigned int)c2) & 0x7FFFFu) | (qa.z & 0xFFF80000u);
            unsigned int s3 = ((((qa.w & 0xFFFu) * 64u) - (unsigned int)c3) & 0x7FFFFu) | (qa.w & 0xFFF80000u);
            unsigned int s4 = ((((qb.x & 0xFFFu) * 64u) - (unsigned int)c4) & 0x7FFFFu) | (qb.x & 0xFFF80000u);
            unsigned int s5 = ((((qb.y & 0xFFFu) * 64u) - (unsigned int)c5) & 0x7FFFFu) | (qb.y & 0xFFF80000u);
            unsigned int s6 = ((((qb.z & 0xFFFu) * 64u) - (unsigned int)c6) & 0x7FFFFu) | (qb.z & 0xFFF80000u);
            unsigned int s7 = ((((qb.w & 0xFFFu) * 64u) - (unsigned int)c7) & 0x7FFFFu) | (qb.w & 0xFFF80000u);
            for (int g = ln; g < tot; g += 64) {
                unsigned int sel = (g < c1) ? s0 : (g < c2) ? s1 : (g < c3) ? s2 : (g < c4) ? s3
                                 : (g < c5) ? s4 : (g < c6) ? s5 : (g < c7) ? s6 : s7;
                unsigned int idx = (sel + (unsigned int)g) & 0x7FFFFu;
                atomicAdd(&acc[nbr[idx]], sel >> 19);
            }
        }
        __syncthreads();
        // linear nibble emit + overflow side-list (col = 16*tid + i2)
        unsigned int wAn = 0, wBn = 0, ovm = 0;
        #pragma unroll
        for (int i2 = 0; i2 < 8; i2++) {
            unsigned int a = acc[16 * tid + i2];
            wAn |= min(a, 15u) << (4 * i2);
            ovm |= (a > 15u ? 1u : 0u) << i2;
        }
        #pragma unroll
        for (int i2 = 0; i2 < 8; i2++) {
            unsigned int a = acc[16 * tid + 8 + i2];
            wBn |= min(a, 15u) << (4 * i2);
            ovm |= (a > 15u ? 1u : 0u) << (8 + i2);
        }
        {
            uint2 nw; nw.x = wAn; nw.y = wBn;
            ((uint2*)(a3n + (size_t)v * 512))[tid] = nw;
        }
        int lov = __popc(ovm);
        int inc2 = lov;
        #pragma unroll
        for (int off = 1; off < 64; off <<= 1) {
            int n = __shfl_up(inc2, off, 64);
            if (ln >= off) inc2 += n;
        }
        if (ln == 63) wsumS[wv] = (unsigned int)inc2;
        __syncthreads();
        unsigned int wpre2 = 0, totS = 0;
        #pragma unroll
        for (int q = 0; q < 4; q++) {
            unsigned int s = wsumS[q];
            if (q < wv) wpre2 += s;
            totS += s;
        }
        unsigned int pos2 = wpre2 + (unsigned int)(inc2 - lov);
        unsigned int* sideR = side + (size_t)v * 192;
        while (ovm) {
            int i2 = __ffs(ovm) - 1;
            ovm &= ovm - 1;
            unsigned int col = (unsigned int)(16 * tid + i2);
            unsigned int a = acc[col];
            if (pos2 < 192u) sideR[pos2] = ((a - 15u) << 16) | col;
            pos2++;
        }
        if (tid == 0) scnt[v] = min(totS, 192u);
    } else {
        // ------------------- cr role -------------------
        unsigned long long* rows = (unsigned long long*)smem;   // [4][64], 2 KB
        int* mems = (int*)(smem + 1024);                        // [4][64], 1 KB
        int v = (bid - NN) * 4 + wv;

        int dv = deg[v];
        int degL = min(dv, 64);
        int c = min(dv + 1, 64);

        int nl = (ln < degL) ? nbr[v * 64 + ln] : 0;
        int isless = (ln < degL && nl < v) ? 1 : 0;
        int pos = isless;
        #pragma unroll
        for (int off = 32; off; off >>= 1) pos += __shfl_xor(pos, off, 64);

        int mem = 0;
        if (ln < c) {
            if (ln < pos)       mem = nl;
            else if (ln == pos) mem = v;
            else                mem = nbr[v * 64 + ln - 1];
        }
        mems[wv * 64 + ln] = mem;
        __syncthreads();

        unsigned long long mask = 0ull;
        {
            const unsigned long long* rowb = abits + (size_t)mem * 64;
            for (int j = 0; j < c; j++) {
                int mj = mems[wv * 64 + j];
                unsigned long long w = rowb[((mj >> 8) << 2) | (mj & 3)];
                mask |= ((w >> ((mj >> 2) & 63)) & 1ull) << j;
            }
        }
        if (ln >= c) mask = 0ull;
        rows[wv * 64 + ln] = mask;
        __syncthreads();

        int tpart = 0;
        float epart = 0.f, wpart = 0.f;
        if (ln < c) {
            unsigned long long mm = mask;
            while (mm) {
                int j = __ffsll(mm) - 1;
                mm &= mm - 1;
                tpart += __popcll(mask & rows[wv * 64 + j]);
            }
            if (ln != pos) {
                int cn = __popcll(rows[wv * 64 + pos] & mask);
                float D2 = (float)cn + 1.0f;
                epart = D2;
                wpart = D2 * (D2 - 1.0f) * 0.5f;
            }
        }
        float es = epart, wsum2 = wpart;
        int ts = tpart;
        #pragma unroll
        for (int off = 32; off; off >>= 1) {
            es += __shfl_xor(es, off, 64);
            wsum2 += __shfl_xor(wsum2, off, 64);
            ts += __shfl_xor(ts, off, 64);
        }

        if (ln == 0) {
            float degf = (float)dv;
            float k = degf + 1.0f;
            float E = 0.5f * (es + degf);
            float W = wsum2 + degf * (degf - 1.0f) * 0.5f;
            float T = (float)ts / 6.0f;
            float f3 = T;
            float f2 = W - 3.0f * T;
            float f1 = E * (k - 2.0f) - 2.0f * f2 - 3.0f * f3;
            float tot2 = k * (k - 1.0f) * (k - 2.0f) / 6.0f;
            float f0 = tot2 - f1 - f2 - f3;
            if (k < 3.0f) { f0 = f1 = f2 = f3 = 0.f; }
            float s = f0 + f1 + f2 + f3 + 1e-10f;
            feats[v * 16 + 0] = f0 / s;
            feats[v * 16 + 1] = f1 / s;
            feats[v * 16 + 2] = f2 / s;
            feats[v * 16 + 3] = f3 / s;
        }
    }
}

// ---------------------------------------------------------------------------
// K4: fused a4-row (register-gather over linear nibble a3 + side-list) +
// top-8 + embedding. v = blockIdx directly (order_k dropped). Max-reduces
// on VALU DPP — no DS-pipe contention from the top-8 extraction.
// ---------------------------------------------------------------------------
__global__ __launch_bounds__(512) void a4row_k(const unsigned int* __restrict__ a3n,
                                               const unsigned int* __restrict__ side,
                                               const unsigned int* __restrict__ scnt,
                                               const int* __restrict__ deg,
                                               const int* __restrict__ nbr,
                                               const float* __restrict__ feats,
                                               const float* __restrict__ e_w,
                                               const float* __restrict__ e_b,
                                               float* __restrict__ x0) {
    __shared__ unsigned int sacc[NN];        // 16 KB u32 side accumulator
    __shared__ unsigned int sbase[64];       // u*512 (word base of a3 row)
    __shared__ unsigned int sbs[64];         // u*192 (side base)
    __shared__ unsigned int sS[64];          // side counts
    __shared__ unsigned int wtops[64];
    int tid = threadIdx.x;
    int wv = tid >> 6, ln = tid & 63;
    int v = blockIdx.x;

    {
        uint4 z = {0u, 0u, 0u, 0u};
        ((uint4*)sacc)[tid] = z;
        ((uint4*)sacc)[tid + 512] = z;
    }
    int dvv = min(deg[v], 64);
    if (tid < dvv) {
        unsigned int u = (unsigned int)nbr[v * 64 + tid];
        sbase[tid] = u * 512u;
        sbs[tid]   = u * 192u;
        sS[tid]    = scnt[u];
    }
    __syncthreads();

    // side scatter (few hundred entries; hides under the base loop)
    for (int i = wv; i < dvv; i += 8) {
        int ns = (int)sS[i];
        const unsigned int* sp = side + sbs[i];
        for (int g2 = ln; g2 < ns; g2 += 64) {
            unsigned int e = sp[g2];
            atomicAdd(&sacc[e & 0xFFFu], e >> 16);
        }
    }

    // base: register gather-accumulate (owner-columns)
    unsigned int aE = 0, aO = 0;
    unsigned int SE0 = 0, SE1 = 0, SO0 = 0, SO1 = 0;
    for (int s0 = 0; s0 < dvv; s0 += 16) {
        int se = min(s0 + 16, dvv);
        for (int s = s0; s < se; s++) {
            unsigned int w = a3n[sbase[s] + (unsigned int)tid];
            aE += w & 0x0F0F0F0Fu;
            aO += (w >> 4) & 0x0F0F0F0Fu;
        }
        SE0 += __builtin_amdgcn_perm(0u, aE, 0x0c010c00u);   // {aE.b0, aE.b1} u16
        SE1 += __builtin_amdgcn_perm(0u, aE, 0x0c030c02u);   // {aE.b2, aE.b3}
        SO0 += __builtin_amdgcn_perm(0u, aO, 0x0c010c00u);
        SO1 += __builtin_amdgcn_perm(0u, aO, 0x0c030c02u);
        aE = 0; aO = 0;
    }
    __syncthreads();

    // merge side sums (cols 8t..8t+7) with register base sums
    uint4 s03 = ((uint4*)sacc)[2 * tid];
    uint4 s47 = ((uint4*)sacc)[2 * tid + 1];
    unsigned int vv[8];
    vv[0] = (SE0 & 0xFFFFu) + s03.x;
    vv[1] = (SO0 & 0xFFFFu) + s03.y;
    vv[2] = (SE0 >> 16)     + s03.z;
    vv[3] = (SO0 >> 16)     + s03.w;
    vv[4] = (SE1 & 0xFFFFu) + s47.x;
    vv[5] = (SO1 & 0xFFFFu) + s47.y;
    vv[6] = (SE1 >> 16)     + s47.z;
    vv[7] = (SO1 >> 16)     + s47.w;

    // per-thread top-8 over the 8 owned columns
    unsigned int best[8];
    #pragma unroll
    for (int q = 0; q < 8; q++) best[q] = 0u;
    #pragma unroll
    for (int m = 0; m < 8; m++) {
        unsigned int val = vv[m];
        if (val > best[7]) {
            best[7] = val;
            #pragma unroll
            for (int s = 7; s > 0; s--) {
                if (best[s] > best[s - 1]) {
                    unsigned int t2 = best[s - 1]; best[s - 1] = best[s]; best[s] = t2;
                } else break;
            }
        }
    }

    // per-wave extract of 8 maxima (DPP max-reduce, VALU-only)
    unsigned int wave_val = 0u;
    #pragma unroll
    for (int r = 0; r < 8; r++) {
        unsigned int m = wave_umax_bcast(best[0]);
        unsigned long long bb = __ballot(best[0] == m);
        int src = __ffsll(bb) - 1;
        if (ln == src) {
            #pragma unroll
            for (int s = 0; s < 7; s++) best[s] = best[s + 1];
            best[7] = 0u;
        }
        if (ln == r) wave_val = m;
    }
    if (ln < 8) wtops[wv * 8 + ln] = wave_val;
    __syncthreads();

    // wave 0: merge 64 candidates, then fused embedding
    if (wv == 0) {
        unsigned int cand = wtops[ln];
        unsigned int myv = 0u;
        #pragma unroll
        for (int r = 0; r < 8; r++) {
            unsigned int m = wave_umax_bcast(cand);
            unsigned long long bb = __ballot(cand == m);
            int src = __ffsll(bb) - 1;
            if (ln == src) cand = 0u;
            if (ln == r) myv = m;
        }
        int d = ln;
        float s = e_b[d];
        s += feats[v * 16 + 0]  * e_w[0 * 64 + d];
        s += feats[v * 16 + 1]  * e_w[1 * 64 + d];
        s += feats[v * 16 + 2]  * e_w[2 * 64 + d];
        s += feats[v * 16 + 3]  * e_w[3 * 64 + d];
        #pragma unroll
        for (int j = 0; j < 8; j++) {
            float mj = (float)(unsigned int)__shfl((int)myv, j, 64);
            s += mj * e_w[(4 + j) * 64 + d];
        }
        s += feats[v * 16 + 12] * e_w[12 * 64 + d];
        s += feats[v * 16 + 13] * e_w[13 * 64 + d];
        s += feats[v * 16 + 14] * e_w[14 * 64 + d];
        x0[(size_t)v * 64 + d] = s;
    }
}

// ---------------------------------------------------------------------------
// K5: one GNN layer, weights LDS-staged. For li==2, accumulate block column
// sums directly into out[64] via fp32 atomics.
// ---------------------------------------------------------------------------
__global__ __launch_bounds__(256) void layer_k(const float* __restrict__ xin,
                                               float* __restrict__ xout,
                                               const float* __restrict__ w1,
                                               const float* __restrict__ b1,
                                               const float* __restrict__ w2,
                                               const float* __restrict__ b2,
                                               const float* __restrict__ eps,
                                               const int* __restrict__ nbr,
                                               const int* __restrict__ deg,
                                               float* __restrict__ out,
                                               int li) {
    __shared__ float wL[4096];                // 16 KB, reused for w1 then w2
    __shared__ float h[4][64], t[4][64];
    int tid = threadIdx.x;
    int wv = tid >> 6, d = tid & 63;
    int v = blockIdx.x * 4 + wv;

    // stage w1 (coalesced float4)
    {
        const float4* src = (const float4*)(w1 + li * 4096);
        #pragma unroll
        for (int i = 0; i < 4; i++) ((float4*)wL)[tid + 256 * i] = src[tid + 256 * i];
    }

    float xv = xin[(size_t)v * 64 + d];
    int dv = min(deg[v], 64);
    const int* nl = nbr + v * 64;
    float agg = 0.f;
    int j = 0;
    for (; j + 4 <= dv; j += 4) {
        int n0 = nl[j], n1 = nl[j + 1], n2 = nl[j + 2], n3 = nl[j + 3];
        float a0 = xin[(size_t)n0 * 64 + d];
        float a1 = xin[(size_t)n1 * 64 + d];
        float a2v = xin[(size_t)n2 * 64 + d];
        float a3 = xin[(size_t)n3 * 64 + d];
        agg += (a0 + a1) + (a2v + a3);
    }
    for (; j < dv; j++) agg += xin[(size_t)nl[j] * 64 + d];
    float hv = (1.0f + eps[li]) * xv + agg;
    h[wv][d] = hv;
    __syncthreads();

    float s = b1[li * 64 + d];
    #pragma unroll 8
    for (int k = 0; k < 64; k++) s += h[wv][k] * wL[k * 64 + d];
    s = fmaxf(s, 0.f);
    t[wv][d] = s;
    __syncthreads();

    // stage w2 (reuse wL)
    {
        const float4* src = (const float4*)(w2 + li * 4096);
        #pragma unroll
        for (int i = 0; i < 4; i++) ((float4*)wL)[tid + 256 * i] = src[tid + 256 * i];
    }
    __syncthreads();

    float o = b2[li * 64 + d];
    #pragma unroll 8
    for (int k = 0; k < 64; k++) o += t[wv][k] * wL[k * 64 + d];
    if (li == 2) {
        h[wv][d] = o;
        __syncthreads();
        if (wv == 0)
            atomicAdd(&out[d], (h[0][d] + h[1][d]) + (h[2][d] + h[3][d]));
    } else {
        xout[(size_t)v * 64 + d] = o;
    }
}

// ---------------------------------------------------------------------------
extern "C" void kernel_launch(void* const* d_in, const int* in_sizes, int n_in,
                              void* d_out, int out_size, void* d_ws, size_t ws_size,
                              hipStream_t stream) {
    const float* adj = (const float*)d_in[0];
    const float* e_w = (const float*)d_in[1];
    const float* e_b = (const float*)d_in[2];
    const float* w1  = (const float*)d_in[3];
    const float* b1  = (const float*)d_in[4];
    const float* w2  = (const float*)d_in[5];
    const float* b2  = (const float*)d_in[6];
    const float* eps = (const float*)d_in[7];
    float* out = (float*)d_out;

    char* ws = (char*)d_ws;
    unsigned int*       a3n     = (unsigned int*)(ws);                  // 8 MB nibble a3
    unsigned int*       side    = (unsigned int*)(ws + 8388608);        // 3 MB side-list
    unsigned int*       scnt    = (unsigned int*)(ws + 11534336);       // 16 KB
    int*                nbr     = (int*)(ws + 25165824);                // 1 MB
    int*                deg     = (int*)(ws + 26214400);                // 16 KB
    float*              feats   = (float*)(ws + 26247168);              // 256 KB
    float*              x0      = (float*)(ws + 26509312);              // 1 MB
    float*              x1      = (float*)(ws + 27557888);              // 1 MB
    unsigned long long* abits   = (unsigned long long*)(ws + 28868608); // 2 MB

    hipMemsetAsync(out, 0, 64 * sizeof(float), stream);
    scan_k<<<1024, 256, 0, stream>>>(adj, nbr, deg, abits, feats);
    cra2_k<<<5120, 256, 0, stream>>>(abits, nbr, deg, a3n, side, scnt, feats);
    a4row_k<<<4096, 512, 0, stream>>>(a3n, side, scnt, deg, nbr, feats, e_w, e_b, x0);
    layer_k<<<1024, 256, 0, stream>>>(x0, x1, w1, b1, w2, b2, eps, nbr, deg, out, 0);
    layer_k<<<1024, 256, 0, stream>>>(x1, x0, w1, b1, w2, b2, eps, nbr, deg, out, 1);
    layer_k<<<1024, 256, 0, stream>>>(x0, x1, w1, b1, w2, b2, eps, nbr, deg, out, 2);
}